// Round 9
// baseline (885.493 us; speedup 1.0000x reference)
//
#include <hip/hip_runtime.h>
#include <hip/hip_bf16.h>
#include <math.h>

constexpr int BB = 256;
constexpr int NCLS = 10;
constexpr int NROUTE = 1152;

typedef __attribute__((ext_vector_type(8))) short s16x8;
typedef __attribute__((ext_vector_type(4))) float f32x4;

__device__ __forceinline__ void gl16(const void* g, void* l) {
  __builtin_amdgcn_global_load_lds(
      (const __attribute__((address_space(1))) void*)g,
      (__attribute__((address_space(3))) void*)l, 16, 0, 0);
}

// ---- conv1: x[256,1,28,28] -> hT[b_l][y*20+x][oc] bf16 hi/lo (NHWC), relu ----
__global__ __launch_bounds__(256) void k_conv1b(const float* __restrict__ x,
    const float* __restrict__ w, const float* __restrict__ bias,
    __hip_bfloat16* __restrict__ hT_hi, __hip_bfloat16* __restrict__ hT_lo,
    int b0) {
  int b_l = blockIdx.x >> 2, q = blockIdx.x & 3;
  __shared__ float sx[784];
  __shared__ float sw[64 * 81];
  int t = threadIdx.x;
  for (int i = t; i < 784; i += 256) sx[i] = x[(size_t)(b0 + b_l) * 784 + i];
  for (int i = t; i < 5184; i += 256) sw[i] = w[(size_t)q * 5184 + i];
  __syncthreads();
  int oc = q * 64 + (t & 63);
  int wv = t >> 6;
  float wreg[81];
#pragma unroll
  for (int k = 0; k < 81; ++k) wreg[k] = sw[(t & 63) * 81 + k];
  float bv = bias[oc];
  for (int st = wv * 10; st < wv * 10 + 10; ++st) {
    int y = st >> 1, x0 = (st & 1) * 10;
    float acc[10];
#pragma unroll
    for (int i = 0; i < 10; ++i) acc[i] = bv;
#pragma unroll
    for (int ky = 0; ky < 9; ++ky) {
      const float* row = &sx[(y + ky) * 28 + x0];
      float rv[18];
#pragma unroll
      for (int i = 0; i < 18; ++i) rv[i] = row[i];
#pragma unroll
      for (int kx = 0; kx < 9; ++kx) {
        float wgt = wreg[ky * 9 + kx];
#pragma unroll
        for (int xi = 0; xi < 10; ++xi) acc[xi] = fmaf(rv[kx + xi], wgt, acc[xi]);
      }
    }
#pragma unroll
    for (int xi = 0; xi < 10; ++xi) {
      float av = fmaxf(acc[xi], 0.f);
      __hip_bfloat16 hi = __float2bfloat16(av);
      float lo = av - __bfloat162float(hi);
      size_t idx = ((size_t)(b_l * 400 + y * 20 + x0 + xi)) * 256 + oc;
      hT_hi[idx] = hi;
      hT_lo[idx] = __float2bfloat16(lo);
    }
  }
}

// ---- weight convert: prim_w[oc][ic][81] f32 -> wt[tap][oc][ic] bf16 hi/lo ----
__global__ __launch_bounds__(256) void k_cvtw(const float* __restrict__ w,
    __hip_bfloat16* __restrict__ wt_hi, __hip_bfloat16* __restrict__ wt_lo) {
  int oc = blockIdx.x >> 2, icq = blockIdx.x & 3;
  __shared__ float sw[5184];
  int t = threadIdx.x;
  const float* src = w + ((size_t)oc * 256 + icq * 64) * 81;
  for (int i = t; i < 5184; i += 256) sw[i] = src[i];
  __syncthreads();
  for (int i = t; i < 5184; i += 256) {
    int tap = i >> 6, icl = i & 63;
    float v = sw[icl * 81 + tap];
    __hip_bfloat16 hi = __float2bfloat16(v);
    float lo = v - __bfloat162float(hi);
    size_t dst = (size_t)tap * 65536 + (size_t)oc * 256 + icq * 64 + icl;
    wt_hi[dst] = hi;
    wt_lo[dst] = __float2bfloat16(lo);
  }
}

// ---- primary caps conv: implicit GEMM BM=128 x BN=128, 4 waves, 64x64/wave.
//      Counted-vmcnt schedule (T3+T4): raw s_barrier, vmcnt(8) steady state,
//      NO vmcnt(0) drain in the main loop. split-K=3; Mblk-per-XCD grouping. ----
constexpr int P4_BUF = 32768;  // A-hi 8K|8K, A-lo 8K|8K (16K), B 16K

__global__ __launch_bounds__(256) void k_prim5(
    const __hip_bfloat16* __restrict__ hT_hi, const __hip_bfloat16* __restrict__ hT_lo,
    const __hip_bfloat16* __restrict__ wt_hi, const __hip_bfloat16* __restrict__ wt_lo,
    float* __restrict__ pout) {
  __shared__ __align__(16) char lds[2 * P4_BUF];
  int x = blockIdx.x & 7, g = blockIdx.x >> 3;
  int nM = (x < 4) ? 5 : 4;
  if (g >= nM * 6) return;
  int Mblk = x + (g / 6) * 8;          // 0..35
  int rem = g % 6;
  int kb = rem % 3, Nblk = rem / 3;    // kb 0..2, Nblk 0..1
  int m0 = Mblk * 128, oc0 = Nblk * 128;
  int t = threadIdx.x, wv = t >> 6, lane = t & 63;
  int q = t & 3;
  int rA = t >> 2;                     // 0..63
  int jswz = q ^ (rA & 3);
  size_t roA0, roA1;
  {
    int m = m0 + rA; int b = m / 36, s = m - b * 36, oy = s / 6, ox = s - oy * 6;
    roA0 = ((size_t)(b * 400 + oy * 40 + ox * 2)) * 512 + (size_t)(jswz * 16);
    m = m0 + rA + 64; b = m / 36; s = m - b * 36; oy = s / 6; ox = s - oy * 6;
    roA1 = ((size_t)(b * 400 + oy * 40 + ox * 2)) * 512 + (size_t)(jswz * 16);
  }
  size_t boB0 = ((size_t)(oc0 + rA)) * 512 + (size_t)(jswz * 16);
  size_t boB1 = ((size_t)(oc0 + rA + 64)) * 512 + (size_t)(jswz * 16);
  const char* hTh = (const char*)hT_hi;
  const char* hTl = (const char*)hT_lo;
  const char* wth = (const char*)wt_hi;
  const char* wtl = (const char*)wt_lo;

  auto stage = [&](int bufi, int s) {
    int tt = s >> 3, icc = s & 7;
    int tap = kb * 27 + tt;
    int ky = tap / 9, kx = tap - ky * 9;
    size_t offA = (size_t)((ky * 20 + kx) * 512 + icc * 64);
    size_t offB = (size_t)tap * 131072 + (size_t)(icc * 64);
    char* d = lds + bufi * P4_BUF + t * 16;
    gl16(hTh + roA0 + offA, d);             // A-hi rows 0-63
    gl16(hTh + roA1 + offA, d + 4096);      // A-hi rows 64-127
    gl16(hTl + roA0 + offA, d + 8192);      // A-lo
    gl16(hTl + roA1 + offA, d + 12288);
    gl16(wth + boB0 + offB, d + 16384);     // B-hi rows 0-63
    gl16(wth + boB1 + offB, d + 20480);     // B-hi rows 64-127
    gl16(wtl + boB0 + offB, d + 24576);     // B-lo
    gl16(wtl + boB1 + offB, d + 28672);
  };

  int wr = wv >> 1, wc = wv & 1;       // 2x2 waves of 64m x 64n
  int lr = lane & 15;
  int swz16 = ((lane >> 4) ^ (lane & 3)) * 16;
  int arow[4], brow[4];
#pragma unroll
  for (int i = 0; i < 4; ++i) arow[i] = (wr * 64 + i * 16 + lr) * 64 + swz16;
#pragma unroll
  for (int j = 0; j < 4; ++j) brow[j] = 16384 + (wc * 64 + j * 16 + lr) * 64 + swz16;

  f32x4 acc[4][4];
#pragma unroll
  for (int i = 0; i < 4; ++i)
#pragma unroll
    for (int j = 0; j < 4; ++j) acc[i][j] = (f32x4){0.f, 0.f, 0.f, 0.f};

  // prologue: buf0 fully staged and drained once
  stage(0, 0);
  asm volatile("s_waitcnt vmcnt(0)" ::: "memory");
  __builtin_amdgcn_s_barrier();
  __builtin_amdgcn_sched_barrier(0);

#pragma unroll 1
  for (int s = 0; s < 215; ++s) {
    int cur = s & 1;
    // issue next tile's 8 loads (into cur^1); prior tile's 8 still may be in flight
    stage(cur ^ 1, s + 1);
    __builtin_amdgcn_sched_barrier(0);
    // wait only the OLDER 8 (the ones filling cur); 8 newest stay in flight
    asm volatile("s_waitcnt vmcnt(8)" ::: "memory");
    __builtin_amdgcn_s_barrier();        // cur fully populated across all waves
    __builtin_amdgcn_sched_barrier(0);
    const char* Ab = lds + cur * P4_BUF;
    s16x8 ah[4], al[4], bh[4], bl[4];
#pragma unroll
    for (int i = 0; i < 4; ++i) {
      ah[i] = *(const s16x8*)(Ab + arow[i]);
      al[i] = *(const s16x8*)(Ab + 8192 + arow[i]);
    }
#pragma unroll
    for (int j = 0; j < 4; ++j) {
      bh[j] = *(const s16x8*)(Ab + brow[j]);
      bl[j] = *(const s16x8*)(Ab + 8192 + brow[j]);
    }
    asm volatile("s_waitcnt lgkmcnt(0)" ::: "memory");
    __builtin_amdgcn_sched_barrier(0);
    __builtin_amdgcn_s_barrier();        // all waves done READING cur -> next iter may DMA into it
    __builtin_amdgcn_sched_barrier(0);
    __builtin_amdgcn_s_setprio(1);
#pragma unroll
    for (int i = 0; i < 4; ++i)
#pragma unroll
      for (int j = 0; j < 4; ++j) {
        acc[i][j] = __builtin_amdgcn_mfma_f32_16x16x32_bf16(ah[i], bh[j], acc[i][j], 0, 0, 0);
        acc[i][j] = __builtin_amdgcn_mfma_f32_16x16x32_bf16(ah[i], bl[j], acc[i][j], 0, 0, 0);
        acc[i][j] = __builtin_amdgcn_mfma_f32_16x16x32_bf16(al[i], bh[j], acc[i][j], 0, 0, 0);
      }
    __builtin_amdgcn_s_setprio(0);
    __builtin_amdgcn_sched_barrier(0);
  }
  // epilogue step s=215 (cur=1): drain its loads fully
  {
    asm volatile("s_waitcnt vmcnt(0)" ::: "memory");
    __builtin_amdgcn_s_barrier();
    __builtin_amdgcn_sched_barrier(0);
    const char* Ab = lds + P4_BUF;
    s16x8 ah[4], al[4], bh[4], bl[4];
#pragma unroll
    for (int i = 0; i < 4; ++i) {
      ah[i] = *(const s16x8*)(Ab + arow[i]);
      al[i] = *(const s16x8*)(Ab + 8192 + arow[i]);
    }
#pragma unroll
    for (int j = 0; j < 4; ++j) {
      bh[j] = *(const s16x8*)(Ab + brow[j]);
      bl[j] = *(const s16x8*)(Ab + 8192 + brow[j]);
    }
    asm volatile("s_waitcnt lgkmcnt(0)" ::: "memory");
    __builtin_amdgcn_sched_barrier(0);
#pragma unroll
    for (int i = 0; i < 4; ++i)
#pragma unroll
      for (int j = 0; j < 4; ++j) {
        acc[i][j] = __builtin_amdgcn_mfma_f32_16x16x32_bf16(ah[i], bh[j], acc[i][j], 0, 0, 0);
        acc[i][j] = __builtin_amdgcn_mfma_f32_16x16x32_bf16(ah[i], bl[j], acc[i][j], 0, 0, 0);
        acc[i][j] = __builtin_amdgcn_mfma_f32_16x16x32_bf16(al[i], bh[j], acc[i][j], 0, 0, 0);
      }
  }
  float* pb = pout + (size_t)kb * (4608 * 256);
#pragma unroll
  for (int i = 0; i < 4; ++i)
#pragma unroll
    for (int j = 0; j < 4; ++j) {
      int n = oc0 + wc * 64 + j * 16 + lr;
#pragma unroll
      for (int qq = 0; qq < 4; ++qq) {
        int m = m0 + wr * 64 + i * 16 + (lane >> 4) * 4 + qq;
        pb[(size_t)m * 256 + n] = acc[i][j][qq];
      }
    }
}

// ---- squash one-pass: block = (s, b_l); 3 partials + bias -> psT[b][r][8] ----
__global__ __launch_bounds__(256) void k_squash3(const float* __restrict__ pout,
    const float* __restrict__ bias, float* __restrict__ psT, int b0) {
  int s = blockIdx.x;        // 0..35
  int b_l = blockIdx.y;      // 0..127
  int t = threadIdx.x;
  int c32 = t & 31;
  __shared__ float ws[4][32];
  __shared__ float buf2[256];
  size_t base = ((size_t)(b_l * 36 + s)) * 256 + t;
  float val = pout[base] + pout[base + 1179648] + pout[base + 2359296] + bias[t];
  float v2 = val * val;
  v2 += __shfl_xor(v2, 32);
  int wvv = t >> 6, lane = t & 63;
  if (lane < 32) ws[wvv][lane] = v2;
  __syncthreads();
  float ss = ws[0][c32] + ws[1][c32] + ws[2][c32] + ws[3][c32];
  float sc = sqrtf(ss) / (1.f + ss);
  buf2[t] = val * sc;
  __syncthreads();
  int cc = t >> 3, jj = t & 7;
  psT[(size_t)(b0 + b_l) * 9216 + (size_t)cc * 288 + s * 8 + jj] =
      buf2[jj * 32 + cc];
}

// ---- fused routing v5: block = (class c, ONE batch); priors in registers ----
__global__ __launch_bounds__(768) void k_route5(const float* __restrict__ psT,
    const float* __restrict__ rw, float* __restrict__ vout) {
  int c = blockIdx.x >> 8;          // class-major
  int b = blockIdx.x & 255;
  int tid = threadIdx.x;
  int wave = tid >> 6, lane = tid & 63;
  int oh = lane >> 5;
  int rs = wave * 32 + (lane & 31); // r = rs + k*384
  __shared__ float lredm[12];
  __shared__ float lreds[12];
  __shared__ float ored[12][2][8];
  __shared__ float osum[16];
  __shared__ float vsq[16];

  float pri[3][8];
  float lgr[3] = {0.f, 0.f, 0.f};
#pragma unroll
  for (int k = 0; k < 3; ++k)
#pragma unroll
    for (int j = 0; j < 8; ++j) pri[k][j] = 0.f;

#pragma unroll
  for (int k = 0; k < 3; ++k) {
    int r = rs + k * 384;
    const float* wr_ = &rw[((size_t)c * 1152 + r) * 128 + oh * 8];
    const float4* pp = (const float4*)&psT[((size_t)b * 1152 + r) * 8];
    float4 pa = pp[0], pb4 = pp[1];
    float ps8[8] = {pa.x, pa.y, pa.z, pa.w, pb4.x, pb4.y, pb4.z, pb4.w};
#pragma unroll
    for (int i = 0; i < 8; ++i) {
      float4 w0 = *(const float4*)&wr_[i * 16];
      float4 w1 = *(const float4*)&wr_[i * 16 + 4];
      float w8[8] = {w0.x, w0.y, w0.z, w0.w, w1.x, w1.y, w1.z, w1.w};
#pragma unroll
      for (int j = 0; j < 8; ++j) pri[k][j] = fmaf(ps8[i], w8[j], pri[k][j]);
    }
  }

  for (int it = 0; it < 3; ++it) {
    float a[8];
    if (it == 0) {
      const float invu = 1.f / 1152.f;
#pragma unroll
      for (int j = 0; j < 8; ++j)
        a[j] = (pri[0][j] + pri[1][j] + pri[2][j]) * invu;
    } else {
      float mx = fmaxf(fmaxf(lgr[0], lgr[1]), lgr[2]);
#pragma unroll
      for (int off = 16; off; off >>= 1) mx = fmaxf(mx, __shfl_xor(mx, off));
      if (lane == 0) lredm[wave] = mx;
      __syncthreads();
      mx = lredm[0];
      for (int w = 1; w < 12; ++w) mx = fmaxf(mx, lredm[w]);
      float er[3];
      float sm = 0.f;
#pragma unroll
      for (int k = 0; k < 3; ++k) {
        er[k] = expf(lgr[k] - mx);
        sm += er[k];
      }
#pragma unroll
      for (int off = 16; off; off >>= 1) sm += __shfl_xor(sm, off);
      if (lane == 0) lreds[wave] = sm;
      __syncthreads();
      float s = 0.f;
      for (int w = 0; w < 12; ++w) s += lreds[w];
      float inv = 1.f / s;
#pragma unroll
      for (int j = 0; j < 8; ++j) a[j] = 0.f;
#pragma unroll
      for (int k = 0; k < 3; ++k) {
        float p = er[k] * inv;
#pragma unroll
        for (int j = 0; j < 8; ++j) a[j] = fmaf(p, pri[k][j], a[j]);
      }
    }
#pragma unroll
    for (int off = 16; off; off >>= 1)
#pragma unroll
      for (int j = 0; j < 8; ++j) a[j] += __shfl_xor(a[j], off);
    if ((lane & 31) == 0) {
#pragma unroll
      for (int j = 0; j < 8; ++j) ored[wave][oh][j] = a[j];
    }
    __syncthreads();
    if (tid < 16) {
      float s = 0.f;
      for (int w = 0; w < 12; ++w) s += ored[w][tid >> 3][tid & 7];
      osum[tid] = s;
    }
    __syncthreads();
    if (tid < 16) {
      float sqv = 0.f;
#pragma unroll
      for (int o = 0; o < 16; ++o) sqv += osum[o] * osum[o];
      float sc = sqrtf(sqv) / (1.f + sqv);
      vsq[tid] = osum[tid] * sc;
    }
    __syncthreads();
    if (it < 2) {
      float vh[8];
#pragma unroll
      for (int j = 0; j < 8; ++j) vh[j] = vsq[oh * 8 + j];
#pragma unroll
      for (int k = 0; k < 3; ++k) {
        float d = 0.f;
#pragma unroll
        for (int j = 0; j < 8; ++j) d = fmaf(pri[k][j], vh[j], d);
        d += __shfl_xor(d, 32);
        lgr[k] += d;
      }
      __syncthreads();
    }
  }
  if (tid < 16) vout[((size_t)c * BB + b) * 16 + tid] = vsq[tid];
}

// ---- classes + argmax; emits am[b] and selected capsule vsel[b][16] ----
__global__ __launch_bounds__(64) void k_cls2(const float* __restrict__ v,
                                             float* __restrict__ classes,
                                             int* __restrict__ am,
                                             float* __restrict__ vsel) {
  int b = blockIdx.x;
  int t = threadIdx.x;
  __shared__ float snrm[10];
  __shared__ int samax;
  if (t < 10) {
    float sq = 0.f;
#pragma unroll
    for (int o = 0; o < 16; ++o) {
      float xx = v[(size_t)(t * BB + b) * 16 + o];
      sq += xx * xx;
    }
    snrm[t] = sqrtf(sq);
  }
  __syncthreads();
  if (t == 0) {
    int amx = 0;
    float bm = snrm[0];
    for (int cc = 1; cc < 10; ++cc)
      if (snrm[cc] > bm) { bm = snrm[cc]; amx = cc; }
    samax = amx;
    am[b] = amx;
  }
  __syncthreads();
  if (t < 10) {
    float mx = snrm[0];
    for (int cc = 1; cc < 10; ++cc) mx = fmaxf(mx, snrm[cc]);
    float sm = 0.f;
    for (int cc = 0; cc < 10; ++cc) sm += expf(snrm[cc] - mx);
    classes[b * 10 + t] = expf(snrm[t] - mx) / sm;
  }
  if (t < 16) vsel[b * 16 + t] = v[((size_t)samax * BB + b) * 16 + t];
}

// ---- fc1 sparse: masked row has only 16 nonzeros (argmax capsule) ----
__global__ __launch_bounds__(512) void k_fc1s(const float* __restrict__ vsel,
    const int* __restrict__ am, const float* __restrict__ w1,
    const float* __restrict__ b1, float* __restrict__ h1) {
  int b = blockIdx.x;
  int n = threadIdx.x;
  __shared__ float sv[16];
  __shared__ int sam;
  if (n < 16) sv[n] = vsel[b * 16 + n];
  if (n == 0) sam = am[b];
  __syncthreads();
  float acc = b1[n];
  int base = sam * 16;
#pragma unroll
  for (int i = 0; i < 16; ++i)
    acc = fmaf(sv[i], w1[(size_t)(base + i) * 512 + n], acc);
  h1[(size_t)b * 512 + n] = fmaxf(acc, 0.f);
}

// ---- fc 32x32-tile GEMM ----
template <int ACT>
__global__ __launch_bounds__(256) void k_fc32(const float* __restrict__ A,
                                              const float* __restrict__ W,
                                              const float* __restrict__ bias,
                                              float* __restrict__ O, int M,
                                              int N, int K) {
  int n0 = blockIdx.x * 32, m0 = blockIdx.y * 32;
  __shared__ float sa[32][33];
  __shared__ float sb[32][34];
  int tid = threadIdx.x, ty = tid >> 4, tx = tid & 15;
  float acc[2][2] = {};
  for (int k0 = 0; k0 < K; k0 += 32) {
    __syncthreads();
    for (int i = tid; i < 1024; i += 256) {
      int m = i >> 5, k = i & 31;
      sa[m][k] = A[(size_t)(m0 + m) * K + k0 + k];
      int kk = i >> 5, n = i & 31;
      int nn = n0 + n;
      sb[kk][n] = (nn < N) ? W[(size_t)(k0 + kk) * N + nn] : 0.f;
    }
    __syncthreads();
#pragma unroll
    for (int k = 0; k < 32; ++k) {
      float a0 = sa[ty * 2 + 0][k];
      float a1 = sa[ty * 2 + 1][k];
      float b0 = sb[k][tx * 2 + 0];
      float b1v = sb[k][tx * 2 + 1];
      acc[0][0] = fmaf(a0, b0, acc[0][0]);
      acc[0][1] = fmaf(a0, b1v, acc[0][1]);
      acc[1][0] = fmaf(a1, b0, acc[1][0]);
      acc[1][1] = fmaf(a1, b1v, acc[1][1]);
    }
  }
#pragma unroll
  for (int i = 0; i < 2; ++i) {
    int m = m0 + ty * 2 + i;
#pragma unroll
    for (int j = 0; j < 2; ++j) {
      int n = n0 + tx * 2 + j;
      if (n < N) {
        float xv = acc[i][j] + bias[n];
        if (ACT == 0)
          xv = fmaxf(xv, 0.f);
        else
          xv = 1.f / (1.f + expf(-xv));
        O[(size_t)m * N + n] = xv;
      }
    }
  }
}

extern "C" void kernel_launch(void* const* d_in, const int* in_sizes, int n_in,
                              void* d_out, int out_size, void* d_ws,
                              size_t ws_size, hipStream_t stream) {
  (void)in_sizes; (void)n_in; (void)out_size; (void)ws_size;
  const float* x       = (const float*)d_in[0];
  const float* conv1_w = (const float*)d_in[1];
  const float* conv1_b = (const float*)d_in[2];
  const float* prim_w  = (const float*)d_in[3];
  const float* prim_b  = (const float*)d_in[4];
  const float* route_w = (const float*)d_in[5];
  const float* dec_w1  = (const float*)d_in[6];
  const float* dec_b1  = (const float*)d_in[7];
  const float* dec_w2  = (const float*)d_in[8];
  const float* dec_b2  = (const float*)d_in[9];
  const float* dec_w3  = (const float*)d_in[10];
  const float* dec_b3  = (const float*)d_in[11];
  float* out = (float*)d_out;

  char* wsb = (char*)d_ws;
  __hip_bfloat16* hT_hi = (__hip_bfloat16*)(wsb);                 // 26,214,400 B
  __hip_bfloat16* hT_lo = (__hip_bfloat16*)(wsb + 26214400);      // 26,214,400 B
  __hip_bfloat16* wt_hi = (__hip_bfloat16*)(wsb + 52428800);      // 10,616,832 B
  __hip_bfloat16* wt_lo = (__hip_bfloat16*)(wsb + 63045632);      // 10,616,832 B
  float* pout = (float*)(wsb + 73662464);                         // 14,155,776 B
  float* psT  = (float*)(wsb + 87818240);                         //  9,437,184 B
  float* v    = (float*)(wsb + 97255424);                         //   163,840 B
  float* h1   = (float*)(wsb + 97419264);                         //   524,288 B
  float* h2   = (float*)(wsb + 97943552);                         // 1,048,576 B
  int*   am   = (int*)  (wsb + 98992128);                         //     4,096 B
  float* vsel = (float*)(wsb + 98996224);                         //    16,384 B

  k_cvtw<<<1024, 256, 0, stream>>>(prim_w, wt_hi, wt_lo);
  for (int hh = 0; hh < 2; ++hh) {
    int b0 = hh * 128;
    k_conv1b<<<512, 256, 0, stream>>>(x, conv1_w, conv1_b, hT_hi, hT_lo, b0);
    k_prim5<<<240, 256, 0, stream>>>(hT_hi, hT_lo, wt_hi, wt_lo, pout);
    k_squash3<<<dim3(36, 128), 256, 0, stream>>>(pout, prim_b, psT, b0);
  }
  k_route5<<<2560, 768, 0, stream>>>(psT, route_w, v);
  k_cls2<<<256, 64, 0, stream>>>(v, out, am, vsel);
  k_fc1s<<<256, 512, 0, stream>>>(vsel, am, dec_w1, dec_b1, h1);
  k_fc32<0><<<dim3(32, 8), 256, 0, stream>>>(h1, dec_w2, dec_b2, h2, 256, 1024, 512);
  k_fc32<1><<<dim3(25, 8), 256, 0, stream>>>(h2, dec_w3, dec_b3, out + 2560, 256, 784, 1024);
}

// Round 10
// 769.854 us; speedup vs baseline: 1.1502x; 1.1502x over previous
//
#include <hip/hip_runtime.h>
#include <hip/hip_bf16.h>
#include <math.h>

constexpr int BB = 256;
constexpr int NCLS = 10;
constexpr int NROUTE = 1152;

typedef __attribute__((ext_vector_type(8))) short s16x8;
typedef __attribute__((ext_vector_type(4))) float f32x4;

// ---- conv1: x[256,1,28,28] -> hT[b_l][y*20+x][oc] bf16 hi/lo (NHWC), relu ----
__global__ __launch_bounds__(256) void k_conv1b(const float* __restrict__ x,
    const float* __restrict__ w, const float* __restrict__ bias,
    __hip_bfloat16* __restrict__ hT_hi, __hip_bfloat16* __restrict__ hT_lo,
    int b0) {
  int b_l = blockIdx.x >> 2, q = blockIdx.x & 3;
  __shared__ float sx[784];
  __shared__ float sw[64 * 81];
  int t = threadIdx.x;
  for (int i = t; i < 784; i += 256) sx[i] = x[(size_t)(b0 + b_l) * 784 + i];
  for (int i = t; i < 5184; i += 256) sw[i] = w[(size_t)q * 5184 + i];
  __syncthreads();
  int oc = q * 64 + (t & 63);
  int wv = t >> 6;
  float wreg[81];
#pragma unroll
  for (int k = 0; k < 81; ++k) wreg[k] = sw[(t & 63) * 81 + k];
  float bv = bias[oc];
  for (int st = wv * 10; st < wv * 10 + 10; ++st) {
    int y = st >> 1, x0 = (st & 1) * 10;
    float acc[10];
#pragma unroll
    for (int i = 0; i < 10; ++i) acc[i] = bv;
#pragma unroll
    for (int ky = 0; ky < 9; ++ky) {
      const float* row = &sx[(y + ky) * 28 + x0];
      float rv[18];
#pragma unroll
      for (int i = 0; i < 18; ++i) rv[i] = row[i];
#pragma unroll
      for (int kx = 0; kx < 9; ++kx) {
        float wgt = wreg[ky * 9 + kx];
#pragma unroll
        for (int xi = 0; xi < 10; ++xi) acc[xi] = fmaf(rv[kx + xi], wgt, acc[xi]);
      }
    }
#pragma unroll
    for (int xi = 0; xi < 10; ++xi) {
      float av = fmaxf(acc[xi], 0.f);
      __hip_bfloat16 hi = __float2bfloat16(av);
      float lo = av - __bfloat162float(hi);
      size_t idx = ((size_t)(b_l * 400 + y * 20 + x0 + xi)) * 256 + oc;
      hT_hi[idx] = hi;
      hT_lo[idx] = __float2bfloat16(lo);
    }
  }
}

// ---- weight convert: prim_w[oc][ic][81] f32 -> wt[tap][oc][ic] bf16 hi/lo ----
__global__ __launch_bounds__(256) void k_cvtw(const float* __restrict__ w,
    __hip_bfloat16* __restrict__ wt_hi, __hip_bfloat16* __restrict__ wt_lo) {
  int oc = blockIdx.x >> 2, icq = blockIdx.x & 3;
  __shared__ float sw[5184];
  int t = threadIdx.x;
  const float* src = w + ((size_t)oc * 256 + icq * 64) * 81;
  for (int i = t; i < 5184; i += 256) sw[i] = src[i];
  __syncthreads();
  for (int i = t; i < 5184; i += 256) {
    int tap = i >> 6, icl = i & 63;
    float v = sw[icl * 81 + tap];
    __hip_bfloat16 hi = __float2bfloat16(v);
    float lo = v - __bfloat162float(hi);
    size_t dst = (size_t)tap * 65536 + (size_t)oc * 256 + icq * 64 + icl;
    wt_hi[dst] = hi;
    wt_lo[dst] = __float2bfloat16(lo);
  }
}

// ---- primary caps conv: implicit GEMM BM=128 x BN=128, 512 thr, 8 waves of
//      64x32. T14 async reg-staging: global->reg loads for step s+1 issued
//      BEFORE compute(s); ds_write after (compiler's vmcnt lands post-compute,
//      so HBM latency hides under MFMA). One barrier/step, no inline asm. ----
constexpr int P6_BUF = 32768;  // A-hi 8K | A-lo 8K | B-hi 8K | B-lo 8K

__global__ __launch_bounds__(512, 2) void k_prim6(
    const __hip_bfloat16* __restrict__ hT_hi, const __hip_bfloat16* __restrict__ hT_lo,
    const __hip_bfloat16* __restrict__ wt_hi, const __hip_bfloat16* __restrict__ wt_lo,
    float* __restrict__ pout) {
  __shared__ __align__(16) char lds[2 * P6_BUF];
  int x = blockIdx.x & 7, g = blockIdx.x >> 3;
  int nM = (x < 4) ? 5 : 4;
  if (g >= nM * 6) return;
  int Mblk = x + (g / 6) * 8;          // 0..35
  int rem = g % 6;
  int kb = rem % 3, Nblk = rem / 3;    // kb 0..2, Nblk 0..1
  int m0 = Mblk * 128, oc0 = Nblk * 128;
  int t = threadIdx.x, wv = t >> 6, lane = t & 63;
  int jswz = (t & 3) ^ ((t >> 2) & 3);
  int rA = t >> 2;  // 0..127
  size_t roA;
  {
    int m = m0 + rA;
    int b = m / 36, s = m - b * 36, oy = s / 6, ox = s - oy * 6;
    roA = ((size_t)(b * 400 + oy * 40 + ox * 2)) * 512 + (size_t)(jswz * 16);
  }
  size_t boB = ((size_t)(oc0 + rA)) * 512 + (size_t)(jswz * 16);
  const char* hTh = (const char*)hT_hi;
  const char* hTl = (const char*)hT_lo;
  const char* wth = (const char*)wt_hi;
  const char* wtl = (const char*)wt_lo;

  int4 rah, ral, rbh, rbl;  // staging registers
  auto loadregs = [&](int s) {
    int tt = s >> 3, icc = s & 7;
    int tap = kb * 27 + tt;
    int ky = tap / 9, kx = tap - ky * 9;
    size_t offA = (size_t)((ky * 20 + kx) * 512 + icc * 64);
    size_t offB = (size_t)tap * 131072 + (size_t)(icc * 64);
    rah = *(const int4*)(hTh + roA + offA);
    ral = *(const int4*)(hTl + roA + offA);
    rbh = *(const int4*)(wth + boB + offB);
    rbl = *(const int4*)(wtl + boB + offB);
  };
  auto writeregs = [&](int bufi) {
    char* d = lds + bufi * P6_BUF + t * 16;   // linear dest: row rA, slice t&3
    *(int4*)(d) = rah;
    *(int4*)(d + 8192) = ral;
    *(int4*)(d + 16384) = rbh;
    *(int4*)(d + 24576) = rbl;
  };

  int wr = wv >> 2, wc = wv & 3;       // 2x4 waves of 64m x 32n
  int lr = lane & 15;
  int swz16 = ((lane >> 4) ^ (lane & 3)) * 16;
  int arow[4], brow[2];
#pragma unroll
  for (int i = 0; i < 4; ++i) arow[i] = (wr * 64 + i * 16 + lr) * 64 + swz16;
#pragma unroll
  for (int j = 0; j < 2; ++j) brow[j] = 16384 + (wc * 32 + j * 16 + lr) * 64 + swz16;

  f32x4 acc[4][2];
#pragma unroll
  for (int i = 0; i < 4; ++i)
#pragma unroll
    for (int j = 0; j < 2; ++j) acc[i][j] = (f32x4){0.f, 0.f, 0.f, 0.f};

  // prologue: stage step 0 into buf0
  loadregs(0);
  writeregs(0);
  __syncthreads();

#pragma unroll 1
  for (int s = 0; s < 216; ++s) {
    int cur = s & 1;
    if (s < 215) loadregs(s + 1);      // in flight during compute
    const char* Ab = lds + cur * P6_BUF;
    s16x8 ah[4], al[4], bh[2], bl[2];
#pragma unroll
    for (int i = 0; i < 4; ++i) {
      ah[i] = *(const s16x8*)(Ab + arow[i]);
      al[i] = *(const s16x8*)(Ab + 8192 + arow[i]);
    }
#pragma unroll
    for (int j = 0; j < 2; ++j) {
      bh[j] = *(const s16x8*)(Ab + brow[j]);
      bl[j] = *(const s16x8*)(Ab + 8192 + brow[j]);
    }
#pragma unroll
    for (int i = 0; i < 4; ++i)
#pragma unroll
      for (int j = 0; j < 2; ++j) {
        acc[i][j] = __builtin_amdgcn_mfma_f32_16x16x32_bf16(ah[i], bh[j], acc[i][j], 0, 0, 0);
        acc[i][j] = __builtin_amdgcn_mfma_f32_16x16x32_bf16(ah[i], bl[j], acc[i][j], 0, 0, 0);
        acc[i][j] = __builtin_amdgcn_mfma_f32_16x16x32_bf16(al[i], bh[j], acc[i][j], 0, 0, 0);
      }
    if (s < 215) writeregs(cur ^ 1);   // compiler waits vmcnt here (post-MFMA)
    __syncthreads();
  }
  float* pb = pout + (size_t)kb * (4608 * 256);
#pragma unroll
  for (int i = 0; i < 4; ++i)
#pragma unroll
    for (int j = 0; j < 2; ++j) {
      int n = oc0 + wc * 32 + j * 16 + lr;
#pragma unroll
      for (int qq = 0; qq < 4; ++qq) {
        int m = m0 + wr * 64 + i * 16 + (lane >> 4) * 4 + qq;
        pb[(size_t)m * 256 + n] = acc[i][j][qq];
      }
    }
}

// ---- squash one-pass: block = (s, b_l); 3 partials + bias -> psT[b][r][8] ----
__global__ __launch_bounds__(256) void k_squash3(const float* __restrict__ pout,
    const float* __restrict__ bias, float* __restrict__ psT, int b0) {
  int s = blockIdx.x;        // 0..35
  int b_l = blockIdx.y;      // 0..127
  int t = threadIdx.x;
  int c32 = t & 31;
  __shared__ float ws[4][32];
  __shared__ float buf2[256];
  size_t base = ((size_t)(b_l * 36 + s)) * 256 + t;
  float val = pout[base] + pout[base + 1179648] + pout[base + 2359296] + bias[t];
  float v2 = val * val;
  v2 += __shfl_xor(v2, 32);
  int wvv = t >> 6, lane = t & 63;
  if (lane < 32) ws[wvv][lane] = v2;
  __syncthreads();
  float ss = ws[0][c32] + ws[1][c32] + ws[2][c32] + ws[3][c32];
  float sc = sqrtf(ss) / (1.f + ss);
  buf2[t] = val * sc;
  __syncthreads();
  int cc = t >> 3, jj = t & 7;
  psT[(size_t)(b0 + b_l) * 9216 + (size_t)cc * 288 + s * 8 + jj] =
      buf2[jj * 32 + cc];
}

// ---- fused routing v5: block = (class c, ONE batch); priors in registers ----
__global__ __launch_bounds__(768) void k_route5(const float* __restrict__ psT,
    const float* __restrict__ rw, float* __restrict__ vout) {
  int c = blockIdx.x >> 8;          // class-major
  int b = blockIdx.x & 255;
  int tid = threadIdx.x;
  int wave = tid >> 6, lane = tid & 63;
  int oh = lane >> 5;
  int rs = wave * 32 + (lane & 31); // r = rs + k*384
  __shared__ float lredm[12];
  __shared__ float lreds[12];
  __shared__ float ored[12][2][8];
  __shared__ float osum[16];
  __shared__ float vsq[16];

  float pri[3][8];
  float lgr[3] = {0.f, 0.f, 0.f};
#pragma unroll
  for (int k = 0; k < 3; ++k)
#pragma unroll
    for (int j = 0; j < 8; ++j) pri[k][j] = 0.f;

#pragma unroll
  for (int k = 0; k < 3; ++k) {
    int r = rs + k * 384;
    const float* wr_ = &rw[((size_t)c * 1152 + r) * 128 + oh * 8];
    const float4* pp = (const float4*)&psT[((size_t)b * 1152 + r) * 8];
    float4 pa = pp[0], pb4 = pp[1];
    float ps8[8] = {pa.x, pa.y, pa.z, pa.w, pb4.x, pb4.y, pb4.z, pb4.w};
#pragma unroll
    for (int i = 0; i < 8; ++i) {
      float4 w0 = *(const float4*)&wr_[i * 16];
      float4 w1 = *(const float4*)&wr_[i * 16 + 4];
      float w8[8] = {w0.x, w0.y, w0.z, w0.w, w1.x, w1.y, w1.z, w1.w};
#pragma unroll
      for (int j = 0; j < 8; ++j) pri[k][j] = fmaf(ps8[i], w8[j], pri[k][j]);
    }
  }

  for (int it = 0; it < 3; ++it) {
    float a[8];
    if (it == 0) {
      const float invu = 1.f / 1152.f;
#pragma unroll
      for (int j = 0; j < 8; ++j)
        a[j] = (pri[0][j] + pri[1][j] + pri[2][j]) * invu;
    } else {
      float mx = fmaxf(fmaxf(lgr[0], lgr[1]), lgr[2]);
#pragma unroll
      for (int off = 16; off; off >>= 1) mx = fmaxf(mx, __shfl_xor(mx, off));
      if (lane == 0) lredm[wave] = mx;
      __syncthreads();
      mx = lredm[0];
      for (int w = 1; w < 12; ++w) mx = fmaxf(mx, lredm[w]);
      float er[3];
      float sm = 0.f;
#pragma unroll
      for (int k = 0; k < 3; ++k) {
        er[k] = expf(lgr[k] - mx);
        sm += er[k];
      }
#pragma unroll
      for (int off = 16; off; off >>= 1) sm += __shfl_xor(sm, off);
      if (lane == 0) lreds[wave] = sm;
      __syncthreads();
      float s = 0.f;
      for (int w = 0; w < 12; ++w) s += lreds[w];
      float inv = 1.f / s;
#pragma unroll
      for (int j = 0; j < 8; ++j) a[j] = 0.f;
#pragma unroll
      for (int k = 0; k < 3; ++k) {
        float p = er[k] * inv;
#pragma unroll
        for (int j = 0; j < 8; ++j) a[j] = fmaf(p, pri[k][j], a[j]);
      }
    }
#pragma unroll
    for (int off = 16; off; off >>= 1)
#pragma unroll
      for (int j = 0; j < 8; ++j) a[j] += __shfl_xor(a[j], off);
    if ((lane & 31) == 0) {
#pragma unroll
      for (int j = 0; j < 8; ++j) ored[wave][oh][j] = a[j];
    }
    __syncthreads();
    if (tid < 16) {
      float s = 0.f;
      for (int w = 0; w < 12; ++w) s += ored[w][tid >> 3][tid & 7];
      osum[tid] = s;
    }
    __syncthreads();
    if (tid < 16) {
      float sqv = 0.f;
#pragma unroll
      for (int o = 0; o < 16; ++o) sqv += osum[o] * osum[o];
      float sc = sqrtf(sqv) / (1.f + sqv);
      vsq[tid] = osum[tid] * sc;
    }
    __syncthreads();
    if (it < 2) {
      float vh[8];
#pragma unroll
      for (int j = 0; j < 8; ++j) vh[j] = vsq[oh * 8 + j];
#pragma unroll
      for (int k = 0; k < 3; ++k) {
        float d = 0.f;
#pragma unroll
        for (int j = 0; j < 8; ++j) d = fmaf(pri[k][j], vh[j], d);
        d += __shfl_xor(d, 32);
        lgr[k] += d;
      }
      __syncthreads();
    }
  }
  if (tid < 16) vout[((size_t)c * BB + b) * 16 + tid] = vsq[tid];
}

// ---- classes + argmax; emits am[b] and selected capsule vsel[b][16] ----
__global__ __launch_bounds__(64) void k_cls2(const float* __restrict__ v,
                                             float* __restrict__ classes,
                                             int* __restrict__ am,
                                             float* __restrict__ vsel) {
  int b = blockIdx.x;
  int t = threadIdx.x;
  __shared__ float snrm[10];
  __shared__ int samax;
  if (t < 10) {
    float sq = 0.f;
#pragma unroll
    for (int o = 0; o < 16; ++o) {
      float xx = v[(size_t)(t * BB + b) * 16 + o];
      sq += xx * xx;
    }
    snrm[t] = sqrtf(sq);
  }
  __syncthreads();
  if (t == 0) {
    int amx = 0;
    float bm = snrm[0];
    for (int cc = 1; cc < 10; ++cc)
      if (snrm[cc] > bm) { bm = snrm[cc]; amx = cc; }
    samax = amx;
    am[b] = amx;
  }
  __syncthreads();
  if (t < 10) {
    float mx = snrm[0];
    for (int cc = 1; cc < 10; ++cc) mx = fmaxf(mx, snrm[cc]);
    float sm = 0.f;
    for (int cc = 0; cc < 10; ++cc) sm += expf(snrm[cc] - mx);
    classes[b * 10 + t] = expf(snrm[t] - mx) / sm;
  }
  if (t < 16) vsel[b * 16 + t] = v[((size_t)samax * BB + b) * 16 + t];
}

// ---- fc1 sparse: masked row has only 16 nonzeros (argmax capsule) ----
__global__ __launch_bounds__(512) void k_fc1s(const float* __restrict__ vsel,
    const int* __restrict__ am, const float* __restrict__ w1,
    const float* __restrict__ b1, float* __restrict__ h1) {
  int b = blockIdx.x;
  int n = threadIdx.x;
  __shared__ float sv[16];
  __shared__ int sam;
  if (n < 16) sv[n] = vsel[b * 16 + n];
  if (n == 0) sam = am[b];
  __syncthreads();
  float acc = b1[n];
  int base = sam * 16;
#pragma unroll
  for (int i = 0; i < 16; ++i)
    acc = fmaf(sv[i], w1[(size_t)(base + i) * 512 + n], acc);
  h1[(size_t)b * 512 + n] = fmaxf(acc, 0.f);
}

// ---- fc 32x32-tile GEMM ----
template <int ACT>
__global__ __launch_bounds__(256) void k_fc32(const float* __restrict__ A,
                                              const float* __restrict__ W,
                                              const float* __restrict__ bias,
                                              float* __restrict__ O, int M,
                                              int N, int K) {
  int n0 = blockIdx.x * 32, m0 = blockIdx.y * 32;
  __shared__ float sa[32][33];
  __shared__ float sb[32][34];
  int tid = threadIdx.x, ty = tid >> 4, tx = tid & 15;
  float acc[2][2] = {};
  for (int k0 = 0; k0 < K; k0 += 32) {
    __syncthreads();
    for (int i = tid; i < 1024; i += 256) {
      int m = i >> 5, k = i & 31;
      sa[m][k] = A[(size_t)(m0 + m) * K + k0 + k];
      int kk = i >> 5, n = i & 31;
      int nn = n0 + n;
      sb[kk][n] = (nn < N) ? W[(size_t)(k0 + kk) * N + nn] : 0.f;
    }
    __syncthreads();
#pragma unroll
    for (int k = 0; k < 32; ++k) {
      float a0 = sa[ty * 2 + 0][k];
      float a1 = sa[ty * 2 + 1][k];
      float b0 = sb[k][tx * 2 + 0];
      float b1v = sb[k][tx * 2 + 1];
      acc[0][0] = fmaf(a0, b0, acc[0][0]);
      acc[0][1] = fmaf(a0, b1v, acc[0][1]);
      acc[1][0] = fmaf(a1, b0, acc[1][0]);
      acc[1][1] = fmaf(a1, b1v, acc[1][1]);
    }
  }
#pragma unroll
  for (int i = 0; i < 2; ++i) {
    int m = m0 + ty * 2 + i;
#pragma unroll
    for (int j = 0; j < 2; ++j) {
      int n = n0 + tx * 2 + j;
      if (n < N) {
        float xv = acc[i][j] + bias[n];
        if (ACT == 0)
          xv = fmaxf(xv, 0.f);
        else
          xv = 1.f / (1.f + expf(-xv));
        O[(size_t)m * N + n] = xv;
      }
    }
  }
}

extern "C" void kernel_launch(void* const* d_in, const int* in_sizes, int n_in,
                              void* d_out, int out_size, void* d_ws,
                              size_t ws_size, hipStream_t stream) {
  (void)in_sizes; (void)n_in; (void)out_size; (void)ws_size;
  const float* x       = (const float*)d_in[0];
  const float* conv1_w = (const float*)d_in[1];
  const float* conv1_b = (const float*)d_in[2];
  const float* prim_w  = (const float*)d_in[3];
  const float* prim_b  = (const float*)d_in[4];
  const float* route_w = (const float*)d_in[5];
  const float* dec_w1  = (const float*)d_in[6];
  const float* dec_b1  = (const float*)d_in[7];
  const float* dec_w2  = (const float*)d_in[8];
  const float* dec_b2  = (const float*)d_in[9];
  const float* dec_w3  = (const float*)d_in[10];
  const float* dec_b3  = (const float*)d_in[11];
  float* out = (float*)d_out;

  char* wsb = (char*)d_ws;
  __hip_bfloat16* hT_hi = (__hip_bfloat16*)(wsb);                 // 26,214,400 B
  __hip_bfloat16* hT_lo = (__hip_bfloat16*)(wsb + 26214400);      // 26,214,400 B
  __hip_bfloat16* wt_hi = (__hip_bfloat16*)(wsb + 52428800);      // 10,616,832 B
  __hip_bfloat16* wt_lo = (__hip_bfloat16*)(wsb + 63045632);      // 10,616,832 B
  float* pout = (float*)(wsb + 73662464);                         // 14,155,776 B
  float* psT  = (float*)(wsb + 87818240);                         //  9,437,184 B
  float* v    = (float*)(wsb + 97255424);                         //   163,840 B
  float* h1   = (float*)(wsb + 97419264);                         //   524,288 B
  float* h2   = (float*)(wsb + 97943552);                         // 1,048,576 B
  int*   am   = (int*)  (wsb + 98992128);                         //     4,096 B
  float* vsel = (float*)(wsb + 98996224);                         //    16,384 B

  k_cvtw<<<1024, 256, 0, stream>>>(prim_w, wt_hi, wt_lo);
  for (int hh = 0; hh < 2; ++hh) {
    int b0 = hh * 128;
    k_conv1b<<<512, 256, 0, stream>>>(x, conv1_w, conv1_b, hT_hi, hT_lo, b0);
    k_prim6<<<240, 512, 0, stream>>>(hT_hi, hT_lo, wt_hi, wt_lo, pout);
    k_squash3<<<dim3(36, 128), 256, 0, stream>>>(pout, prim_b, psT, b0);
  }
  k_route5<<<2560, 768, 0, stream>>>(psT, route_w, v);
  k_cls2<<<256, 64, 0, stream>>>(v, out, am, vsel);
  k_fc1s<<<256, 512, 0, stream>>>(vsel, am, dec_w1, dec_b1, h1);
  k_fc32<0><<<dim3(32, 8), 256, 0, stream>>>(h1, dec_w2, dec_b2, h2, 256, 1024, 512);
  k_fc32<1><<<dim3(25, 8), 256, 0, stream>>>(h2, dec_w3, dec_b3, out + 2560, 256, 784, 1024);
}

// Round 11
// 722.758 us; speedup vs baseline: 1.2252x; 1.0652x over previous
//
#include <hip/hip_runtime.h>
#include <hip/hip_bf16.h>
#include <math.h>

constexpr int BB = 256;
constexpr int NCLS = 10;
constexpr int NROUTE = 1152;

typedef __attribute__((ext_vector_type(8))) short s16x8;
typedef __attribute__((ext_vector_type(4))) float f32x4;

// ---- conv1: x[256,1,28,28] -> hT[b_l][y*20+x][oc] bf16 hi/lo (NHWC), relu ----
__global__ __launch_bounds__(256) void k_conv1b(const float* __restrict__ x,
    const float* __restrict__ w, const float* __restrict__ bias,
    __hip_bfloat16* __restrict__ hT_hi, __hip_bfloat16* __restrict__ hT_lo,
    int b0) {
  int b_l = blockIdx.x >> 2, q = blockIdx.x & 3;
  __shared__ float sx[784];
  __shared__ float sw[64 * 81];
  int t = threadIdx.x;
  for (int i = t; i < 784; i += 256) sx[i] = x[(size_t)(b0 + b_l) * 784 + i];
  for (int i = t; i < 5184; i += 256) sw[i] = w[(size_t)q * 5184 + i];
  __syncthreads();
  int oc = q * 64 + (t & 63);
  int wv = t >> 6;
  float wreg[81];
#pragma unroll
  for (int k = 0; k < 81; ++k) wreg[k] = sw[(t & 63) * 81 + k];
  float bv = bias[oc];
  for (int st = wv * 10; st < wv * 10 + 10; ++st) {
    int y = st >> 1, x0 = (st & 1) * 10;
    float acc[10];
#pragma unroll
    for (int i = 0; i < 10; ++i) acc[i] = bv;
#pragma unroll
    for (int ky = 0; ky < 9; ++ky) {
      const float* row = &sx[(y + ky) * 28 + x0];
      float rv[18];
#pragma unroll
      for (int i = 0; i < 18; ++i) rv[i] = row[i];
#pragma unroll
      for (int kx = 0; kx < 9; ++kx) {
        float wgt = wreg[ky * 9 + kx];
#pragma unroll
        for (int xi = 0; xi < 10; ++xi) acc[xi] = fmaf(rv[kx + xi], wgt, acc[xi]);
      }
    }
#pragma unroll
    for (int xi = 0; xi < 10; ++xi) {
      float av = fmaxf(acc[xi], 0.f);
      __hip_bfloat16 hi = __float2bfloat16(av);
      float lo = av - __bfloat162float(hi);
      size_t idx = ((size_t)(b_l * 400 + y * 20 + x0 + xi)) * 256 + oc;
      hT_hi[idx] = hi;
      hT_lo[idx] = __float2bfloat16(lo);
    }
  }
}

// ---- weight convert: prim_w[oc][ic][81] f32 -> wt[tap][oc][ic] bf16 hi/lo ----
__global__ __launch_bounds__(256) void k_cvtw(const float* __restrict__ w,
    __hip_bfloat16* __restrict__ wt_hi, __hip_bfloat16* __restrict__ wt_lo) {
  int oc = blockIdx.x >> 2, icq = blockIdx.x & 3;
  __shared__ float sw[5184];
  int t = threadIdx.x;
  const float* src = w + ((size_t)oc * 256 + icq * 64) * 81;
  for (int i = t; i < 5184; i += 256) sw[i] = src[i];
  __syncthreads();
  for (int i = t; i < 5184; i += 256) {
    int tap = i >> 6, icl = i & 63;
    float v = sw[icl * 81 + tap];
    __hip_bfloat16 hi = __float2bfloat16(v);
    float lo = v - __bfloat162float(hi);
    size_t dst = (size_t)tap * 65536 + (size_t)oc * 256 + icq * 64 + icl;
    wt_hi[dst] = hi;
    wt_lo[dst] = __float2bfloat16(lo);
  }
}

// ---- primary caps conv: implicit GEMM BM=128 x BN=128, 512 thr, 8 waves of
//      64x32, T14 async reg-staging (round-10 proven, ~m97 structural ceiling) ----
constexpr int P6_BUF = 32768;  // A-hi 8K | A-lo 8K | B-hi 8K | B-lo 8K

__global__ __launch_bounds__(512, 2) void k_prim6(
    const __hip_bfloat16* __restrict__ hT_hi, const __hip_bfloat16* __restrict__ hT_lo,
    const __hip_bfloat16* __restrict__ wt_hi, const __hip_bfloat16* __restrict__ wt_lo,
    float* __restrict__ pout) {
  __shared__ __align__(16) char lds[2 * P6_BUF];
  int x = blockIdx.x & 7, g = blockIdx.x >> 3;
  int nM = (x < 4) ? 5 : 4;
  if (g >= nM * 6) return;
  int Mblk = x + (g / 6) * 8;          // 0..35
  int rem = g % 6;
  int kb = rem % 3, Nblk = rem / 3;    // kb 0..2, Nblk 0..1
  int m0 = Mblk * 128, oc0 = Nblk * 128;
  int t = threadIdx.x, wv = t >> 6, lane = t & 63;
  int jswz = (t & 3) ^ ((t >> 2) & 3);
  int rA = t >> 2;  // 0..127
  size_t roA;
  {
    int m = m0 + rA;
    int b = m / 36, s = m - b * 36, oy = s / 6, ox = s - oy * 6;
    roA = ((size_t)(b * 400 + oy * 40 + ox * 2)) * 512 + (size_t)(jswz * 16);
  }
  size_t boB = ((size_t)(oc0 + rA)) * 512 + (size_t)(jswz * 16);
  const char* hTh = (const char*)hT_hi;
  const char* hTl = (const char*)hT_lo;
  const char* wth = (const char*)wt_hi;
  const char* wtl = (const char*)wt_lo;

  int4 rah, ral, rbh, rbl;  // staging registers
  auto loadregs = [&](int s) {
    int tt = s >> 3, icc = s & 7;
    int tap = kb * 27 + tt;
    int ky = tap / 9, kx = tap - ky * 9;
    size_t offA = (size_t)((ky * 20 + kx) * 512 + icc * 64);
    size_t offB = (size_t)tap * 131072 + (size_t)(icc * 64);
    rah = *(const int4*)(hTh + roA + offA);
    ral = *(const int4*)(hTl + roA + offA);
    rbh = *(const int4*)(wth + boB + offB);
    rbl = *(const int4*)(wtl + boB + offB);
  };
  auto writeregs = [&](int bufi) {
    char* d = lds + bufi * P6_BUF + t * 16;
    *(int4*)(d) = rah;
    *(int4*)(d + 8192) = ral;
    *(int4*)(d + 16384) = rbh;
    *(int4*)(d + 24576) = rbl;
  };

  int wr = wv >> 2, wc = wv & 3;       // 2x4 waves of 64m x 32n
  int lr = lane & 15;
  int swz16 = ((lane >> 4) ^ (lane & 3)) * 16;
  int arow[4], brow[2];
#pragma unroll
  for (int i = 0; i < 4; ++i) arow[i] = (wr * 64 + i * 16 + lr) * 64 + swz16;
#pragma unroll
  for (int j = 0; j < 2; ++j) brow[j] = 16384 + (wc * 32 + j * 16 + lr) * 64 + swz16;

  f32x4 acc[4][2];
#pragma unroll
  for (int i = 0; i < 4; ++i)
#pragma unroll
    for (int j = 0; j < 2; ++j) acc[i][j] = (f32x4){0.f, 0.f, 0.f, 0.f};

  loadregs(0);
  writeregs(0);
  __syncthreads();

#pragma unroll 1
  for (int s = 0; s < 216; ++s) {
    int cur = s & 1;
    if (s < 215) loadregs(s + 1);
    const char* Ab = lds + cur * P6_BUF;
    s16x8 ah[4], al[4], bh[2], bl[2];
#pragma unroll
    for (int i = 0; i < 4; ++i) {
      ah[i] = *(const s16x8*)(Ab + arow[i]);
      al[i] = *(const s16x8*)(Ab + 8192 + arow[i]);
    }
#pragma unroll
    for (int j = 0; j < 2; ++j) {
      bh[j] = *(const s16x8*)(Ab + brow[j]);
      bl[j] = *(const s16x8*)(Ab + 8192 + brow[j]);
    }
#pragma unroll
    for (int i = 0; i < 4; ++i)
#pragma unroll
      for (int j = 0; j < 2; ++j) {
        acc[i][j] = __builtin_amdgcn_mfma_f32_16x16x32_bf16(ah[i], bh[j], acc[i][j], 0, 0, 0);
        acc[i][j] = __builtin_amdgcn_mfma_f32_16x16x32_bf16(ah[i], bl[j], acc[i][j], 0, 0, 0);
        acc[i][j] = __builtin_amdgcn_mfma_f32_16x16x32_bf16(al[i], bh[j], acc[i][j], 0, 0, 0);
      }
    if (s < 215) writeregs(cur ^ 1);
    __syncthreads();
  }
  float* pb = pout + (size_t)kb * (4608 * 256);
#pragma unroll
  for (int i = 0; i < 4; ++i)
#pragma unroll
    for (int j = 0; j < 2; ++j) {
      int n = oc0 + wc * 32 + j * 16 + lr;
#pragma unroll
      for (int qq = 0; qq < 4; ++qq) {
        int m = m0 + wr * 64 + i * 16 + (lane >> 4) * 4 + qq;
        pb[(size_t)m * 256 + n] = acc[i][j][qq];
      }
    }
}

// ---- squash one-pass: block = (s, b_l); 3 partials + bias -> psT[b][r][8] ----
__global__ __launch_bounds__(256) void k_squash3(const float* __restrict__ pout,
    const float* __restrict__ bias, float* __restrict__ psT, int b0) {
  int s = blockIdx.x;        // 0..35
  int b_l = blockIdx.y;      // 0..127
  int t = threadIdx.x;
  int c32 = t & 31;
  __shared__ float ws[4][32];
  __shared__ float buf2[256];
  size_t base = ((size_t)(b_l * 36 + s)) * 256 + t;
  float val = pout[base] + pout[base + 1179648] + pout[base + 2359296] + bias[t];
  float v2 = val * val;
  v2 += __shfl_xor(v2, 32);
  int wvv = t >> 6, lane = t & 63;
  if (lane < 32) ws[wvv][lane] = v2;
  __syncthreads();
  float ss = ws[0][c32] + ws[1][c32] + ws[2][c32] + ws[3][c32];
  float sc = sqrtf(ss) / (1.f + ss);
  buf2[t] = val * sc;
  __syncthreads();
  int cc = t >> 3, jj = t & 7;
  psT[(size_t)(b0 + b_l) * 9216 + (size_t)cc * 288 + s * 8 + jj] =
      buf2[jj * 32 + cc];
}

// ---- fused routing v6: block = (class c, 2 batches); o-quartered priors in
//      registers: pri[2][6][4] = 48 regs, live set ~78 < 84 (no spill).
//      No max-subtraction (|logits| <= ~12, f32-safe); 10 barriers total. ----
__global__ __launch_bounds__(768) void k_route6(const float* __restrict__ psT,
    const float* __restrict__ rw, float* __restrict__ vout) {
  int c = blockIdx.x >> 7;          // 10 classes
  int bp = blockIdx.x & 127;
  int b0 = bp * 2;
  int tid = threadIdx.x;
  int wave = tid >> 6, lane = tid & 63;
  int rl = lane & 15;               // r-lane within wave
  int oq = lane >> 4;               // o-quarter 0..3
  int rs = wave * 16 + rl;          // 0..191; r = rs + k*192, k=0..5
  __shared__ float lreds[12][2];
  __shared__ float ored[12][4][2][4];
  __shared__ float vsq[2][16];

  float pri[2][6][4];
  float lgr[2][6];
#pragma unroll
  for (int b = 0; b < 2; ++b)
#pragma unroll
    for (int k = 0; k < 6; ++k) {
      lgr[b][k] = 0.f;
#pragma unroll
      for (int j = 0; j < 4; ++j) pri[b][k][j] = 0.f;
    }

  for (int k = 0; k < 6; ++k) {
    int r = rs + k * 192;
    const float* wr_ = &rw[((size_t)c * 1152 + r) * 128 + oq * 4];
    const float4* pp = (const float4*)&psT[((size_t)b0 * 1152 + r) * 8];
    const float4* pq = (const float4*)&psT[((size_t)(b0 + 1) * 1152 + r) * 8];
    float4 pa0 = pp[0], pa1 = pp[1], pb0 = pq[0], pb1 = pq[1];
    float psa[8] = {pa0.x, pa0.y, pa0.z, pa0.w, pa1.x, pa1.y, pa1.z, pa1.w};
    float psb[8] = {pb0.x, pb0.y, pb0.z, pb0.w, pb1.x, pb1.y, pb1.z, pb1.w};
#pragma unroll
    for (int i = 0; i < 8; ++i) {
      float4 w4 = *(const float4*)&wr_[i * 16];
      float wa[4] = {w4.x, w4.y, w4.z, w4.w};
#pragma unroll
      for (int j = 0; j < 4; ++j) {
        pri[0][k][j] = fmaf(psa[i], wa[j], pri[0][k][j]);
        pri[1][k][j] = fmaf(psb[i], wa[j], pri[1][k][j]);
      }
    }
  }

  for (int it = 0; it < 3; ++it) {
    float a[2][4];
    if (it == 0) {
      const float invu = 1.f / 1152.f;
#pragma unroll
      for (int b = 0; b < 2; ++b)
#pragma unroll
        for (int j = 0; j < 4; ++j) {
          float s = 0.f;
#pragma unroll
          for (int k = 0; k < 6; ++k) s += pri[b][k][j];
          a[b][j] = s * invu;
        }
    } else {
      float sm[2] = {0.f, 0.f};
#pragma unroll
      for (int b = 0; b < 2; ++b)
#pragma unroll
        for (int k = 0; k < 6; ++k) sm[b] += __expf(lgr[b][k]);
#pragma unroll
      for (int off = 1; off < 16; off <<= 1)
#pragma unroll
        for (int b = 0; b < 2; ++b) sm[b] += __shfl_xor(sm[b], off);
      if (lane == 0) { lreds[wave][0] = sm[0]; lreds[wave][1] = sm[1]; }
      __syncthreads();
      float inv[2];
#pragma unroll
      for (int b = 0; b < 2; ++b) {
        float s = 0.f;
        for (int w = 0; w < 12; ++w) s += lreds[w][b];
        inv[b] = 1.f / s;
      }
#pragma unroll
      for (int b = 0; b < 2; ++b)
#pragma unroll
        for (int j = 0; j < 4; ++j) a[b][j] = 0.f;
#pragma unroll
      for (int k = 0; k < 6; ++k)
#pragma unroll
        for (int b = 0; b < 2; ++b) {
          float p = __expf(lgr[b][k]) * inv[b];
#pragma unroll
          for (int j = 0; j < 4; ++j) a[b][j] = fmaf(p, pri[b][k][j], a[b][j]);
        }
    }
    // reduce over the 16 r-lanes of this (wave, oq)
#pragma unroll
    for (int off = 1; off < 16; off <<= 1)
#pragma unroll
      for (int b = 0; b < 2; ++b)
#pragma unroll
        for (int j = 0; j < 4; ++j) a[b][j] += __shfl_xor(a[b][j], off);
    if (rl == 0) {
#pragma unroll
      for (int b = 0; b < 2; ++b)
#pragma unroll
        for (int j = 0; j < 4; ++j) ored[wave][oq][b][j] = a[b][j];
    }
    __syncthreads();
    if (tid < 32) {
      int b = tid >> 4, o = tid & 15;
      float s = 0.f;
      for (int w = 0; w < 12; ++w) s += ored[w][o >> 2][b][o & 3];
      float s2 = s * s;
#pragma unroll
      for (int off = 1; off < 16; off <<= 1) s2 += __shfl_xor(s2, off);
      float sc = sqrtf(s2) / (1.f + s2);
      vsq[b][o] = s * sc;
    }
    __syncthreads();
    if (it < 2) {
#pragma unroll
      for (int b = 0; b < 2; ++b) {
        float vh[4];
#pragma unroll
        for (int j = 0; j < 4; ++j) vh[j] = vsq[b][oq * 4 + j];
#pragma unroll
        for (int k = 0; k < 6; ++k) {
          float d = 0.f;
#pragma unroll
          for (int j = 0; j < 4; ++j) d = fmaf(pri[b][k][j], vh[j], d);
          d += __shfl_xor(d, 16);
          d += __shfl_xor(d, 32);
          lgr[b][k] += d;
        }
      }
      __syncthreads();
    }
  }
  if (tid < 32) {
    int b = tid >> 4, o = tid & 15;
    vout[((size_t)c * BB + (b0 + b)) * 16 + o] = vsq[b][o];
  }
}

// ---- head: classes softmax + argmax + sparse fc1 (fused, one launch) ----
__global__ __launch_bounds__(512) void k_head(const float* __restrict__ v,
    const float* __restrict__ w1, const float* __restrict__ b1,
    float* __restrict__ classes, float* __restrict__ h1) {
  int b = blockIdx.x;
  int t = threadIdx.x;
  __shared__ float snrm[10];
  __shared__ float sv[16];
  __shared__ int sam;
  if (t < 10) {
    float sq = 0.f;
#pragma unroll
    for (int o = 0; o < 16; ++o) {
      float xx = v[(size_t)(t * BB + b) * 16 + o];
      sq += xx * xx;
    }
    snrm[t] = sqrtf(sq);
  }
  __syncthreads();
  if (t == 0) {
    int amx = 0;
    float bm = snrm[0];
    for (int cc = 1; cc < 10; ++cc)
      if (snrm[cc] > bm) { bm = snrm[cc]; amx = cc; }
    sam = amx;
  }
  __syncthreads();
  if (t < 10) {
    float mx = snrm[0];
    for (int cc = 1; cc < 10; ++cc) mx = fmaxf(mx, snrm[cc]);
    float smv = 0.f;
    for (int cc = 0; cc < 10; ++cc) smv += __expf(snrm[cc] - mx);
    classes[b * 10 + t] = __expf(snrm[t] - mx) / smv;
  }
  if (t < 16) sv[t] = v[((size_t)sam * BB + b) * 16 + t];
  __syncthreads();
  float acc = b1[t];
  int base = sam * 16;
#pragma unroll
  for (int i = 0; i < 16; ++i)
    acc = fmaf(sv[i], w1[(size_t)(base + i) * 512 + t], acc);
  h1[(size_t)b * 512 + t] = fmaxf(acc, 0.f);
}

// ---- fc 32x32-tile GEMM ----
template <int ACT>
__global__ __launch_bounds__(256) void k_fc32(const float* __restrict__ A,
                                              const float* __restrict__ W,
                                              const float* __restrict__ bias,
                                              float* __restrict__ O, int M,
                                              int N, int K) {
  int n0 = blockIdx.x * 32, m0 = blockIdx.y * 32;
  __shared__ float sa[32][33];
  __shared__ float sb[32][34];
  int tid = threadIdx.x, ty = tid >> 4, tx = tid & 15;
  float acc[2][2] = {};
  for (int k0 = 0; k0 < K; k0 += 32) {
    __syncthreads();
    for (int i = tid; i < 1024; i += 256) {
      int m = i >> 5, k = i & 31;
      sa[m][k] = A[(size_t)(m0 + m) * K + k0 + k];
      int kk = i >> 5, n = i & 31;
      int nn = n0 + n;
      sb[kk][n] = (nn < N) ? W[(size_t)(k0 + kk) * N + nn] : 0.f;
    }
    __syncthreads();
#pragma unroll
    for (int k = 0; k < 32; ++k) {
      float a0 = sa[ty * 2 + 0][k];
      float a1 = sa[ty * 2 + 1][k];
      float b0 = sb[k][tx * 2 + 0];
      float b1v = sb[k][tx * 2 + 1];
      acc[0][0] = fmaf(a0, b0, acc[0][0]);
      acc[0][1] = fmaf(a0, b1v, acc[0][1]);
      acc[1][0] = fmaf(a1, b0, acc[1][0]);
      acc[1][1] = fmaf(a1, b1v, acc[1][1]);
    }
  }
#pragma unroll
  for (int i = 0; i < 2; ++i) {
    int m = m0 + ty * 2 + i;
#pragma unroll
    for (int j = 0; j < 2; ++j) {
      int n = n0 + tx * 2 + j;
      if (n < N) {
        float xv = acc[i][j] + bias[n];
        if (ACT == 0)
          xv = fmaxf(xv, 0.f);
        else
          xv = 1.f / (1.f + expf(-xv));
        O[(size_t)m * N + n] = xv;
      }
    }
  }
}

extern "C" void kernel_launch(void* const* d_in, const int* in_sizes, int n_in,
                              void* d_out, int out_size, void* d_ws,
                              size_t ws_size, hipStream_t stream) {
  (void)in_sizes; (void)n_in; (void)out_size; (void)ws_size;
  const float* x       = (const float*)d_in[0];
  const float* conv1_w = (const float*)d_in[1];
  const float* conv1_b = (const float*)d_in[2];
  const float* prim_w  = (const float*)d_in[3];
  const float* prim_b  = (const float*)d_in[4];
  const float* route_w = (const float*)d_in[5];
  const float* dec_w1  = (const float*)d_in[6];
  const float* dec_b1  = (const float*)d_in[7];
  const float* dec_w2  = (const float*)d_in[8];
  const float* dec_b2  = (const float*)d_in[9];
  const float* dec_w3  = (const float*)d_in[10];
  const float* dec_b3  = (const float*)d_in[11];
  float* out = (float*)d_out;

  char* wsb = (char*)d_ws;
  __hip_bfloat16* hT_hi = (__hip_bfloat16*)(wsb);                 // 26,214,400 B
  __hip_bfloat16* hT_lo = (__hip_bfloat16*)(wsb + 26214400);      // 26,214,400 B
  __hip_bfloat16* wt_hi = (__hip_bfloat16*)(wsb + 52428800);      // 10,616,832 B
  __hip_bfloat16* wt_lo = (__hip_bfloat16*)(wsb + 63045632);      // 10,616,832 B
  float* pout = (float*)(wsb + 73662464);                         // 14,155,776 B
  float* psT  = (float*)(wsb + 87818240);                         //  9,437,184 B
  float* v    = (float*)(wsb + 97255424);                         //   163,840 B
  float* h1   = (float*)(wsb + 97419264);                         //   524,288 B
  float* h2   = (float*)(wsb + 97943552);                         // 1,048,576 B

  k_cvtw<<<1024, 256, 0, stream>>>(prim_w, wt_hi, wt_lo);
  for (int hh = 0; hh < 2; ++hh) {
    int b0 = hh * 128;
    k_conv1b<<<512, 256, 0, stream>>>(x, conv1_w, conv1_b, hT_hi, hT_lo, b0);
    k_prim6<<<240, 512, 0, stream>>>(hT_hi, hT_lo, wt_hi, wt_lo, pout);
    k_squash3<<<dim3(36, 128), 256, 0, stream>>>(pout, prim_b, psT, b0);
  }
  k_route6<<<1280, 768, 0, stream>>>(psT, route_w, v);
  k_head<<<256, 512, 0, stream>>>(v, dec_w1, dec_b1, out, h1);
  k_fc32<0><<<dim3(32, 8), 256, 0, stream>>>(h1, dec_w2, dec_b2, h2, 256, 1024, 512);
  k_fc32<1><<<dim3(25, 8), 256, 0, stream>>>(h2, dec_w3, dec_b3, out + 2560, 256, 784, 1024);
}

// Round 12
// 674.643 us; speedup vs baseline: 1.3125x; 1.0713x over previous
//
#include <hip/hip_runtime.h>
#include <hip/hip_bf16.h>
#include <math.h>

constexpr int BB = 256;
constexpr int NCLS = 10;
constexpr int NROUTE = 1152;

typedef __attribute__((ext_vector_type(8))) short s16x8;
typedef __attribute__((ext_vector_type(4))) float f32x4;

// ---- conv1: x[256,1,28,28] -> hT[b_l][y*20+x][oc] bf16 hi/lo (NHWC), relu ----
__global__ __launch_bounds__(256) void k_conv1b(const float* __restrict__ x,
    const float* __restrict__ w, const float* __restrict__ bias,
    __hip_bfloat16* __restrict__ hT_hi, __hip_bfloat16* __restrict__ hT_lo,
    int b0) {
  int b_l = blockIdx.x >> 2, q = blockIdx.x & 3;
  __shared__ float sx[784];
  __shared__ float sw[64 * 81];
  int t = threadIdx.x;
  for (int i = t; i < 784; i += 256) sx[i] = x[(size_t)(b0 + b_l) * 784 + i];
  for (int i = t; i < 5184; i += 256) sw[i] = w[(size_t)q * 5184 + i];
  __syncthreads();
  int oc = q * 64 + (t & 63);
  int wv = t >> 6;
  float wreg[81];
#pragma unroll
  for (int k = 0; k < 81; ++k) wreg[k] = sw[(t & 63) * 81 + k];
  float bv = bias[oc];
  for (int st = wv * 10; st < wv * 10 + 10; ++st) {
    int y = st >> 1, x0 = (st & 1) * 10;
    float acc[10];
#pragma unroll
    for (int i = 0; i < 10; ++i) acc[i] = bv;
#pragma unroll
    for (int ky = 0; ky < 9; ++ky) {
      const float* row = &sx[(y + ky) * 28 + x0];
      float rv[18];
#pragma unroll
      for (int i = 0; i < 18; ++i) rv[i] = row[i];
#pragma unroll
      for (int kx = 0; kx < 9; ++kx) {
        float wgt = wreg[ky * 9 + kx];
#pragma unroll
        for (int xi = 0; xi < 10; ++xi) acc[xi] = fmaf(rv[kx + xi], wgt, acc[xi]);
      }
    }
#pragma unroll
    for (int xi = 0; xi < 10; ++xi) {
      float av = fmaxf(acc[xi], 0.f);
      __hip_bfloat16 hi = __float2bfloat16(av);
      float lo = av - __bfloat162float(hi);
      size_t idx = ((size_t)(b_l * 400 + y * 20 + x0 + xi)) * 256 + oc;
      hT_hi[idx] = hi;
      hT_lo[idx] = __float2bfloat16(lo);
    }
  }
}

// ---- weight convert: prim_w[oc][ic][81] f32 -> wt[tap][oc][ic] bf16 hi/lo ----
__global__ __launch_bounds__(256) void k_cvtw(const float* __restrict__ w,
    __hip_bfloat16* __restrict__ wt_hi, __hip_bfloat16* __restrict__ wt_lo) {
  int oc = blockIdx.x >> 2, icq = blockIdx.x & 3;
  __shared__ float sw[5184];
  int t = threadIdx.x;
  const float* src = w + ((size_t)oc * 256 + icq * 64) * 81;
  for (int i = t; i < 5184; i += 256) sw[i] = src[i];
  __syncthreads();
  for (int i = t; i < 5184; i += 256) {
    int tap = i >> 6, icl = i & 63;
    float v = sw[icl * 81 + tap];
    __hip_bfloat16 hi = __float2bfloat16(v);
    float lo = v - __bfloat162float(hi);
    size_t dst = (size_t)tap * 65536 + (size_t)oc * 256 + icq * 64 + icl;
    wt_hi[dst] = hi;
    wt_lo[dst] = __float2bfloat16(lo);
  }
}

// ---- primary caps conv: implicit GEMM BM=128 x BN=128, 512 thr, 8 waves of
//      64x32, T14 reg-staging. SPLIT-K=9 (9 taps/block): 648 blocks => ~2.5
//      blocks/CU co-resident; barrier-drain stalls of one block overlap with
//      compute of another. Geometry/staging identical to round-10 proven. ----
constexpr int P6_BUF = 32768;  // A-hi 8K | A-lo 8K | B-hi 8K | B-lo 8K

__global__ __launch_bounds__(512, 2) void k_prim6(
    const __hip_bfloat16* __restrict__ hT_hi, const __hip_bfloat16* __restrict__ hT_lo,
    const __hip_bfloat16* __restrict__ wt_hi, const __hip_bfloat16* __restrict__ wt_lo,
    float* __restrict__ pout) {
  __shared__ __align__(16) char lds[2 * P6_BUF];
  int x = blockIdx.x & 7, g = blockIdx.x >> 3;
  int nM = (x < 4) ? 5 : 4;
  if (g >= nM * 18) return;
  int Mblk = x + (g / 18) * 8;         // 0..35
  int rem = g % 18;
  int kb = rem % 9, Nblk = rem / 9;    // kb 0..8 (9 taps each), Nblk 0..1
  int m0 = Mblk * 128, oc0 = Nblk * 128;
  int t = threadIdx.x, wv = t >> 6, lane = t & 63;
  int jswz = (t & 3) ^ ((t >> 2) & 3);
  int rA = t >> 2;  // 0..127
  size_t roA;
  {
    int m = m0 + rA;
    int b = m / 36, s = m - b * 36, oy = s / 6, ox = s - oy * 6;
    roA = ((size_t)(b * 400 + oy * 40 + ox * 2)) * 512 + (size_t)(jswz * 16);
  }
  size_t boB = ((size_t)(oc0 + rA)) * 512 + (size_t)(jswz * 16);
  const char* hTh = (const char*)hT_hi;
  const char* hTl = (const char*)hT_lo;
  const char* wth = (const char*)wt_hi;
  const char* wtl = (const char*)wt_lo;

  int4 rah, ral, rbh, rbl;  // staging registers
  auto loadregs = [&](int s) {
    int tt = s >> 3, icc = s & 7;
    int tap = kb * 9 + tt;
    int ky = tap / 9, kx = tap - ky * 9;
    size_t offA = (size_t)((ky * 20 + kx) * 512 + icc * 64);
    size_t offB = (size_t)tap * 131072 + (size_t)(icc * 64);
    rah = *(const int4*)(hTh + roA + offA);
    ral = *(const int4*)(hTl + roA + offA);
    rbh = *(const int4*)(wth + boB + offB);
    rbl = *(const int4*)(wtl + boB + offB);
  };
  auto writeregs = [&](int bufi) {
    char* d = lds + bufi * P6_BUF + t * 16;
    *(int4*)(d) = rah;
    *(int4*)(d + 8192) = ral;
    *(int4*)(d + 16384) = rbh;
    *(int4*)(d + 24576) = rbl;
  };

  int wr = wv >> 2, wc = wv & 3;       // 2x4 waves of 64m x 32n
  int lr = lane & 15;
  int swz16 = ((lane >> 4) ^ (lane & 3)) * 16;
  int arow[4], brow[2];
#pragma unroll
  for (int i = 0; i < 4; ++i) arow[i] = (wr * 64 + i * 16 + lr) * 64 + swz16;
#pragma unroll
  for (int j = 0; j < 2; ++j) brow[j] = 16384 + (wc * 32 + j * 16 + lr) * 64 + swz16;

  f32x4 acc[4][2];
#pragma unroll
  for (int i = 0; i < 4; ++i)
#pragma unroll
    for (int j = 0; j < 2; ++j) acc[i][j] = (f32x4){0.f, 0.f, 0.f, 0.f};

  loadregs(0);
  writeregs(0);
  __syncthreads();

#pragma unroll 1
  for (int s = 0; s < 72; ++s) {
    int cur = s & 1;
    if (s < 71) loadregs(s + 1);
    const char* Ab = lds + cur * P6_BUF;
    s16x8 ah[4], al[4], bh[2], bl[2];
#pragma unroll
    for (int i = 0; i < 4; ++i) {
      ah[i] = *(const s16x8*)(Ab + arow[i]);
      al[i] = *(const s16x8*)(Ab + 8192 + arow[i]);
    }
#pragma unroll
    for (int j = 0; j < 2; ++j) {
      bh[j] = *(const s16x8*)(Ab + brow[j]);
      bl[j] = *(const s16x8*)(Ab + 8192 + brow[j]);
    }
#pragma unroll
    for (int i = 0; i < 4; ++i)
#pragma unroll
      for (int j = 0; j < 2; ++j) {
        acc[i][j] = __builtin_amdgcn_mfma_f32_16x16x32_bf16(ah[i], bh[j], acc[i][j], 0, 0, 0);
        acc[i][j] = __builtin_amdgcn_mfma_f32_16x16x32_bf16(ah[i], bl[j], acc[i][j], 0, 0, 0);
        acc[i][j] = __builtin_amdgcn_mfma_f32_16x16x32_bf16(al[i], bh[j], acc[i][j], 0, 0, 0);
      }
    if (s < 71) writeregs(cur ^ 1);
    __syncthreads();
  }
  float* pb = pout + (size_t)kb * (4608 * 256);
#pragma unroll
  for (int i = 0; i < 4; ++i)
#pragma unroll
    for (int j = 0; j < 2; ++j) {
      int n = oc0 + wc * 32 + j * 16 + lr;
#pragma unroll
      for (int qq = 0; qq < 4; ++qq) {
        int m = m0 + wr * 64 + i * 16 + (lane >> 4) * 4 + qq;
        pb[(size_t)m * 256 + n] = acc[i][j][qq];
      }
    }
}

// ---- squash one-pass: block = (s, b_l); 9 partials + bias -> psT[b][r][8] ----
__global__ __launch_bounds__(256) void k_squash3(const float* __restrict__ pout,
    const float* __restrict__ bias, float* __restrict__ psT, int b0) {
  int s = blockIdx.x;        // 0..35
  int b_l = blockIdx.y;      // 0..127
  int t = threadIdx.x;
  int c32 = t & 31;
  __shared__ float ws[4][32];
  __shared__ float buf2[256];
  size_t base = ((size_t)(b_l * 36 + s)) * 256 + t;
  float val = bias[t];
#pragma unroll
  for (int k = 0; k < 9; ++k) val += pout[base + (size_t)k * 1179648];
  float v2 = val * val;
  v2 += __shfl_xor(v2, 32);
  int wvv = t >> 6, lane = t & 63;
  if (lane < 32) ws[wvv][lane] = v2;
  __syncthreads();
  float ss = ws[0][c32] + ws[1][c32] + ws[2][c32] + ws[3][c32];
  float sc = sqrtf(ss) / (1.f + ss);
  buf2[t] = val * sc;
  __syncthreads();
  int cc = t >> 3, jj = t & 7;
  psT[(size_t)(b0 + b_l) * 9216 + (size_t)cc * 288 + s * 8 + jj] =
      buf2[jj * 32 + cc];
}

// ---- fused routing v6: block = (class c, 2 batches); o-quartered priors ----
__global__ __launch_bounds__(768) void k_route6(const float* __restrict__ psT,
    const float* __restrict__ rw, float* __restrict__ vout) {
  int c = blockIdx.x >> 7;
  int bp = blockIdx.x & 127;
  int b0 = bp * 2;
  int tid = threadIdx.x;
  int wave = tid >> 6, lane = tid & 63;
  int rl = lane & 15;
  int oq = lane >> 4;
  int rs = wave * 16 + rl;          // 0..191; r = rs + k*192
  __shared__ float lreds[12][2];
  __shared__ float ored[12][4][2][4];
  __shared__ float vsq[2][16];

  float pri[2][6][4];
  float lgr[2][6];
#pragma unroll
  for (int b = 0; b < 2; ++b)
#pragma unroll
    for (int k = 0; k < 6; ++k) {
      lgr[b][k] = 0.f;
#pragma unroll
      for (int j = 0; j < 4; ++j) pri[b][k][j] = 0.f;
    }

  for (int k = 0; k < 6; ++k) {
    int r = rs + k * 192;
    const float* wr_ = &rw[((size_t)c * 1152 + r) * 128 + oq * 4];
    const float4* pp = (const float4*)&psT[((size_t)b0 * 1152 + r) * 8];
    const float4* pq = (const float4*)&psT[((size_t)(b0 + 1) * 1152 + r) * 8];
    float4 pa0 = pp[0], pa1 = pp[1], pb0 = pq[0], pb1 = pq[1];
    float psa[8] = {pa0.x, pa0.y, pa0.z, pa0.w, pa1.x, pa1.y, pa1.z, pa1.w};
    float psb[8] = {pb0.x, pb0.y, pb0.z, pb0.w, pb1.x, pb1.y, pb1.z, pb1.w};
#pragma unroll
    for (int i = 0; i < 8; ++i) {
      float4 w4 = *(const float4*)&wr_[i * 16];
      float wa[4] = {w4.x, w4.y, w4.z, w4.w};
#pragma unroll
      for (int j = 0; j < 4; ++j) {
        pri[0][k][j] = fmaf(psa[i], wa[j], pri[0][k][j]);
        pri[1][k][j] = fmaf(psb[i], wa[j], pri[1][k][j]);
      }
    }
  }

  for (int it = 0; it < 3; ++it) {
    float a[2][4];
    if (it == 0) {
      const float invu = 1.f / 1152.f;
#pragma unroll
      for (int b = 0; b < 2; ++b)
#pragma unroll
        for (int j = 0; j < 4; ++j) {
          float s = 0.f;
#pragma unroll
          for (int k = 0; k < 6; ++k) s += pri[b][k][j];
          a[b][j] = s * invu;
        }
    } else {
      float sm[2] = {0.f, 0.f};
#pragma unroll
      for (int b = 0; b < 2; ++b)
#pragma unroll
        for (int k = 0; k < 6; ++k) sm[b] += __expf(lgr[b][k]);
#pragma unroll
      for (int off = 1; off < 16; off <<= 1)
#pragma unroll
        for (int b = 0; b < 2; ++b) sm[b] += __shfl_xor(sm[b], off);
      if (lane == 0) { lreds[wave][0] = sm[0]; lreds[wave][1] = sm[1]; }
      __syncthreads();
      float inv[2];
#pragma unroll
      for (int b = 0; b < 2; ++b) {
        float s = 0.f;
        for (int w = 0; w < 12; ++w) s += lreds[w][b];
        inv[b] = 1.f / s;
      }
#pragma unroll
      for (int b = 0; b < 2; ++b)
#pragma unroll
        for (int j = 0; j < 4; ++j) a[b][j] = 0.f;
#pragma unroll
      for (int k = 0; k < 6; ++k)
#pragma unroll
        for (int b = 0; b < 2; ++b) {
          float p = __expf(lgr[b][k]) * inv[b];
#pragma unroll
          for (int j = 0; j < 4; ++j) a[b][j] = fmaf(p, pri[b][k][j], a[b][j]);
        }
    }
#pragma unroll
    for (int off = 1; off < 16; off <<= 1)
#pragma unroll
      for (int b = 0; b < 2; ++b)
#pragma unroll
        for (int j = 0; j < 4; ++j) a[b][j] += __shfl_xor(a[b][j], off);
    if (rl == 0) {
#pragma unroll
      for (int b = 0; b < 2; ++b)
#pragma unroll
        for (int j = 0; j < 4; ++j) ored[wave][oq][b][j] = a[b][j];
    }
    __syncthreads();
    if (tid < 32) {
      int b = tid >> 4, o = tid & 15;
      float s = 0.f;
      for (int w = 0; w < 12; ++w) s += ored[w][o >> 2][b][o & 3];
      float s2 = s * s;
#pragma unroll
      for (int off = 1; off < 16; off <<= 1) s2 += __shfl_xor(s2, off);
      float sc = sqrtf(s2) / (1.f + s2);
      vsq[b][o] = s * sc;
    }
    __syncthreads();
    if (it < 2) {
#pragma unroll
      for (int b = 0; b < 2; ++b) {
        float vh[4];
#pragma unroll
        for (int j = 0; j < 4; ++j) vh[j] = vsq[b][oq * 4 + j];
#pragma unroll
        for (int k = 0; k < 6; ++k) {
          float d = 0.f;
#pragma unroll
          for (int j = 0; j < 4; ++j) d = fmaf(pri[b][k][j], vh[j], d);
          d += __shfl_xor(d, 16);
          d += __shfl_xor(d, 32);
          lgr[b][k] += d;
        }
      }
      __syncthreads();
    }
  }
  if (tid < 32) {
    int b = tid >> 4, o = tid & 15;
    vout[((size_t)c * BB + (b0 + b)) * 16 + o] = vsq[b][o];
  }
}

// ---- head: classes softmax + argmax + sparse fc1 (fused) ----
__global__ __launch_bounds__(512) void k_head(const float* __restrict__ v,
    const float* __restrict__ w1, const float* __restrict__ b1,
    float* __restrict__ classes, float* __restrict__ h1) {
  int b = blockIdx.x;
  int t = threadIdx.x;
  __shared__ float snrm[10];
  __shared__ float sv[16];
  __shared__ int sam;
  if (t < 10) {
    float sq = 0.f;
#pragma unroll
    for (int o = 0; o < 16; ++o) {
      float xx = v[(size_t)(t * BB + b) * 16 + o];
      sq += xx * xx;
    }
    snrm[t] = sqrtf(sq);
  }
  __syncthreads();
  if (t == 0) {
    int amx = 0;
    float bm = snrm[0];
    for (int cc = 1; cc < 10; ++cc)
      if (snrm[cc] > bm) { bm = snrm[cc]; amx = cc; }
    sam = amx;
  }
  __syncthreads();
  if (t < 10) {
    float mx = snrm[0];
    for (int cc = 1; cc < 10; ++cc) mx = fmaxf(mx, snrm[cc]);
    float smv = 0.f;
    for (int cc = 0; cc < 10; ++cc) smv += __expf(snrm[cc] - mx);
    classes[b * 10 + t] = __expf(snrm[t] - mx) / smv;
  }
  if (t < 16) sv[t] = v[((size_t)sam * BB + b) * 16 + t];
  __syncthreads();
  float acc = b1[t];
  int base = sam * 16;
#pragma unroll
  for (int i = 0; i < 16; ++i)
    acc = fmaf(sv[i], w1[(size_t)(base + i) * 512 + t], acc);
  h1[(size_t)b * 512 + t] = fmaxf(acc, 0.f);
}

// ---- fc 32x32-tile GEMM ----
template <int ACT>
__global__ __launch_bounds__(256) void k_fc32(const float* __restrict__ A,
                                              const float* __restrict__ W,
                                              const float* __restrict__ bias,
                                              float* __restrict__ O, int M,
                                              int N, int K) {
  int n0 = blockIdx.x * 32, m0 = blockIdx.y * 32;
  __shared__ float sa[32][33];
  __shared__ float sb[32][34];
  int tid = threadIdx.x, ty = tid >> 4, tx = tid & 15;
  float acc[2][2] = {};
  for (int k0 = 0; k0 < K; k0 += 32) {
    __syncthreads();
    for (int i = tid; i < 1024; i += 256) {
      int m = i >> 5, k = i & 31;
      sa[m][k] = A[(size_t)(m0 + m) * K + k0 + k];
      int kk = i >> 5, n = i & 31;
      int nn = n0 + n;
      sb[kk][n] = (nn < N) ? W[(size_t)(k0 + kk) * N + nn] : 0.f;
    }
    __syncthreads();
#pragma unroll
    for (int k = 0; k < 32; ++k) {
      float a0 = sa[ty * 2 + 0][k];
      float a1 = sa[ty * 2 + 1][k];
      float b0 = sb[k][tx * 2 + 0];
      float b1v = sb[k][tx * 2 + 1];
      acc[0][0] = fmaf(a0, b0, acc[0][0]);
      acc[0][1] = fmaf(a0, b1v, acc[0][1]);
      acc[1][0] = fmaf(a1, b0, acc[1][0]);
      acc[1][1] = fmaf(a1, b1v, acc[1][1]);
    }
  }
#pragma unroll
  for (int i = 0; i < 2; ++i) {
    int m = m0 + ty * 2 + i;
#pragma unroll
    for (int j = 0; j < 2; ++j) {
      int n = n0 + tx * 2 + j;
      if (n < N) {
        float xv = acc[i][j] + bias[n];
        if (ACT == 0)
          xv = fmaxf(xv, 0.f);
        else
          xv = 1.f / (1.f + expf(-xv));
        O[(size_t)m * N + n] = xv;
      }
    }
  }
}

extern "C" void kernel_launch(void* const* d_in, const int* in_sizes, int n_in,
                              void* d_out, int out_size, void* d_ws,
                              size_t ws_size, hipStream_t stream) {
  (void)in_sizes; (void)n_in; (void)out_size; (void)ws_size;
  const float* x       = (const float*)d_in[0];
  const float* conv1_w = (const float*)d_in[1];
  const float* conv1_b = (const float*)d_in[2];
  const float* prim_w  = (const float*)d_in[3];
  const float* prim_b  = (const float*)d_in[4];
  const float* route_w = (const float*)d_in[5];
  const float* dec_w1  = (const float*)d_in[6];
  const float* dec_b1  = (const float*)d_in[7];
  const float* dec_w2  = (const float*)d_in[8];
  const float* dec_b2  = (const float*)d_in[9];
  const float* dec_w3  = (const float*)d_in[10];
  const float* dec_b3  = (const float*)d_in[11];
  float* out = (float*)d_out;

  char* wsb = (char*)d_ws;
  __hip_bfloat16* hT_hi = (__hip_bfloat16*)(wsb);                 // 26,214,400 B
  __hip_bfloat16* hT_lo = (__hip_bfloat16*)(wsb + 26214400);      // 26,214,400 B
  __hip_bfloat16* wt_hi = (__hip_bfloat16*)(wsb + 52428800);      // 10,616,832 B
  __hip_bfloat16* wt_lo = (__hip_bfloat16*)(wsb + 63045632);      // 10,616,832 B
  float* pout = (float*)(wsb + 73662464);                         // 42,467,328 B (9 partials)
  float* psT  = (float*)(wsb + 116129792);                        //  9,437,184 B
  float* v    = (float*)(wsb + 125566976);                        //    163,840 B
  float* h1   = (float*)(wsb + 125730816);                        //    524,288 B
  float* h2   = (float*)(wsb + 126255104);                        //  1,048,576 B

  k_cvtw<<<1024, 256, 0, stream>>>(prim_w, wt_hi, wt_lo);
  for (int hh = 0; hh < 2; ++hh) {
    int b0 = hh * 128;
    k_conv1b<<<512, 256, 0, stream>>>(x, conv1_w, conv1_b, hT_hi, hT_lo, b0);
    k_prim6<<<720, 512, 0, stream>>>(hT_hi, hT_lo, wt_hi, wt_lo, pout);
    k_squash3<<<dim3(36, 128), 256, 0, stream>>>(pout, prim_b, psT, b0);
  }
  k_route6<<<1280, 768, 0, stream>>>(psT, route_w, v);
  k_head<<<256, 512, 0, stream>>>(v, dec_w1, dec_b1, out, h1);
  k_fc32<0><<<dim3(32, 8), 256, 0, stream>>>(h1, dec_w2, dec_b2, h2, 256, 1024, 512);
  k_fc32<1><<<dim3(25, 8), 256, 0, stream>>>(h2, dec_w3, dec_b3, out + 2560, 256, 784, 1024);
}

// Round 13
// 669.364 us; speedup vs baseline: 1.3229x; 1.0079x over previous
//
#include <hip/hip_runtime.h>
#include <hip/hip_bf16.h>
#include <math.h>

constexpr int BB = 256;
constexpr int NCLS = 10;
constexpr int NROUTE = 1152;

typedef __attribute__((ext_vector_type(8))) short s16x8;
typedef __attribute__((ext_vector_type(4))) float f32x4;

// ---- conv1: x[256,1,28,28] -> hT[b_l][y*20+x][oc] bf16 hi/lo (NHWC), relu ----
__global__ __launch_bounds__(256) void k_conv1b(const float* __restrict__ x,
    const float* __restrict__ w, const float* __restrict__ bias,
    __hip_bfloat16* __restrict__ hT_hi, __hip_bfloat16* __restrict__ hT_lo,
    int b0) {
  int b_l = blockIdx.x >> 2, q = blockIdx.x & 3;
  __shared__ float sx[784];
  __shared__ float sw[64 * 81];
  int t = threadIdx.x;
  for (int i = t; i < 784; i += 256) sx[i] = x[(size_t)(b0 + b_l) * 784 + i];
  for (int i = t; i < 5184; i += 256) sw[i] = w[(size_t)q * 5184 + i];
  __syncthreads();
  int oc = q * 64 + (t & 63);
  int wv = t >> 6;
  float wreg[81];
#pragma unroll
  for (int k = 0; k < 81; ++k) wreg[k] = sw[(t & 63) * 81 + k];
  float bv = bias[oc];
  for (int st = wv * 10; st < wv * 10 + 10; ++st) {
    int y = st >> 1, x0 = (st & 1) * 10;
    float acc[10];
#pragma unroll
    for (int i = 0; i < 10; ++i) acc[i] = bv;
#pragma unroll
    for (int ky = 0; ky < 9; ++ky) {
      const float* row = &sx[(y + ky) * 28 + x0];
      float rv[18];
#pragma unroll
      for (int i = 0; i < 18; ++i) rv[i] = row[i];
#pragma unroll
      for (int kx = 0; kx < 9; ++kx) {
        float wgt = wreg[ky * 9 + kx];
#pragma unroll
        for (int xi = 0; xi < 10; ++xi) acc[xi] = fmaf(rv[kx + xi], wgt, acc[xi]);
      }
    }
#pragma unroll
    for (int xi = 0; xi < 10; ++xi) {
      float av = fmaxf(acc[xi], 0.f);
      __hip_bfloat16 hi = __float2bfloat16(av);
      float lo = av - __bfloat162float(hi);
      size_t idx = ((size_t)(b_l * 400 + y * 20 + x0 + xi)) * 256 + oc;
      hT_hi[idx] = hi;
      hT_lo[idx] = __float2bfloat16(lo);
    }
  }
}

// ---- weight convert: prim_w[oc][ic][81] f32 -> wt[tap][oc][ic] bf16 hi/lo ----
__global__ __launch_bounds__(256) void k_cvtw(const float* __restrict__ w,
    __hip_bfloat16* __restrict__ wt_hi, __hip_bfloat16* __restrict__ wt_lo) {
  int oc = blockIdx.x >> 2, icq = blockIdx.x & 3;
  __shared__ float sw[5184];
  int t = threadIdx.x;
  const float* src = w + ((size_t)oc * 256 + icq * 64) * 81;
  for (int i = t; i < 5184; i += 256) sw[i] = src[i];
  __syncthreads();
  for (int i = t; i < 5184; i += 256) {
    int tap = i >> 6, icl = i & 63;
    float v = sw[icl * 81 + tap];
    __hip_bfloat16 hi = __float2bfloat16(v);
    float lo = v - __bfloat162float(hi);
    size_t dst = (size_t)tap * 65536 + (size_t)oc * 256 + icq * 64 + icl;
    wt_hi[dst] = hi;
    wt_lo[dst] = __float2bfloat16(lo);
  }
}

// ---- primary caps conv: implicit GEMM BM=128 x BN=128, 512 thr, 8 waves of
//      64x32, T14 reg-staging, split-K=9 (round-12 proven; ~874 TF = m97
//      structural ceiling for the 2-barrier structure) ----
constexpr int P6_BUF = 32768;  // A-hi 8K | A-lo 8K | B-hi 8K | B-lo 8K

__global__ __launch_bounds__(512, 2) void k_prim6(
    const __hip_bfloat16* __restrict__ hT_hi, const __hip_bfloat16* __restrict__ hT_lo,
    const __hip_bfloat16* __restrict__ wt_hi, const __hip_bfloat16* __restrict__ wt_lo,
    float* __restrict__ pout) {
  __shared__ __align__(16) char lds[2 * P6_BUF];
  int x = blockIdx.x & 7, g = blockIdx.x >> 3;
  int nM = (x < 4) ? 5 : 4;
  if (g >= nM * 18) return;
  int Mblk = x + (g / 18) * 8;         // 0..35
  int rem = g % 18;
  int kb = rem % 9, Nblk = rem / 9;    // kb 0..8 (9 taps each), Nblk 0..1
  int m0 = Mblk * 128, oc0 = Nblk * 128;
  int t = threadIdx.x, wv = t >> 6, lane = t & 63;
  int jswz = (t & 3) ^ ((t >> 2) & 3);
  int rA = t >> 2;  // 0..127
  size_t roA;
  {
    int m = m0 + rA;
    int b = m / 36, s = m - b * 36, oy = s / 6, ox = s - oy * 6;
    roA = ((size_t)(b * 400 + oy * 40 + ox * 2)) * 512 + (size_t)(jswz * 16);
  }
  size_t boB = ((size_t)(oc0 + rA)) * 512 + (size_t)(jswz * 16);
  const char* hTh = (const char*)hT_hi;
  const char* hTl = (const char*)hT_lo;
  const char* wth = (const char*)wt_hi;
  const char* wtl = (const char*)wt_lo;

  int4 rah, ral, rbh, rbl;  // staging registers
  auto loadregs = [&](int s) {
    int tt = s >> 3, icc = s & 7;
    int tap = kb * 9 + tt;
    int ky = tap / 9, kx = tap - ky * 9;
    size_t offA = (size_t)((ky * 20 + kx) * 512 + icc * 64);
    size_t offB = (size_t)tap * 131072 + (size_t)(icc * 64);
    rah = *(const int4*)(hTh + roA + offA);
    ral = *(const int4*)(hTl + roA + offA);
    rbh = *(const int4*)(wth + boB + offB);
    rbl = *(const int4*)(wtl + boB + offB);
  };
  auto writeregs = [&](int bufi) {
    char* d = lds + bufi * P6_BUF + t * 16;
    *(int4*)(d) = rah;
    *(int4*)(d + 8192) = ral;
    *(int4*)(d + 16384) = rbh;
    *(int4*)(d + 24576) = rbl;
  };

  int wr = wv >> 2, wc = wv & 3;       // 2x4 waves of 64m x 32n
  int lr = lane & 15;
  int swz16 = ((lane >> 4) ^ (lane & 3)) * 16;
  int arow[4], brow[2];
#pragma unroll
  for (int i = 0; i < 4; ++i) arow[i] = (wr * 64 + i * 16 + lr) * 64 + swz16;
#pragma unroll
  for (int j = 0; j < 2; ++j) brow[j] = 16384 + (wc * 32 + j * 16 + lr) * 64 + swz16;

  f32x4 acc[4][2];
#pragma unroll
  for (int i = 0; i < 4; ++i)
#pragma unroll
    for (int j = 0; j < 2; ++j) acc[i][j] = (f32x4){0.f, 0.f, 0.f, 0.f};

  loadregs(0);
  writeregs(0);
  __syncthreads();

#pragma unroll 1
  for (int s = 0; s < 72; ++s) {
    int cur = s & 1;
    if (s < 71) loadregs(s + 1);
    const char* Ab = lds + cur * P6_BUF;
    s16x8 ah[4], al[4], bh[2], bl[2];
#pragma unroll
    for (int i = 0; i < 4; ++i) {
      ah[i] = *(const s16x8*)(Ab + arow[i]);
      al[i] = *(const s16x8*)(Ab + 8192 + arow[i]);
    }
#pragma unroll
    for (int j = 0; j < 2; ++j) {
      bh[j] = *(const s16x8*)(Ab + brow[j]);
      bl[j] = *(const s16x8*)(Ab + 8192 + brow[j]);
    }
#pragma unroll
    for (int i = 0; i < 4; ++i)
#pragma unroll
      for (int j = 0; j < 2; ++j) {
        acc[i][j] = __builtin_amdgcn_mfma_f32_16x16x32_bf16(ah[i], bh[j], acc[i][j], 0, 0, 0);
        acc[i][j] = __builtin_amdgcn_mfma_f32_16x16x32_bf16(ah[i], bl[j], acc[i][j], 0, 0, 0);
        acc[i][j] = __builtin_amdgcn_mfma_f32_16x16x32_bf16(al[i], bh[j], acc[i][j], 0, 0, 0);
      }
    if (s < 71) writeregs(cur ^ 1);
    __syncthreads();
  }
  float* pb = pout + (size_t)kb * (4608 * 256);
#pragma unroll
  for (int i = 0; i < 4; ++i)
#pragma unroll
    for (int j = 0; j < 2; ++j) {
      int n = oc0 + wc * 32 + j * 16 + lr;
#pragma unroll
      for (int qq = 0; qq < 4; ++qq) {
        int m = m0 + wr * 64 + i * 16 + (lane >> 4) * 4 + qq;
        pb[(size_t)m * 256 + n] = acc[i][j][qq];
      }
    }
}

// ---- squash one-pass: block = (s, b_l); 9 partials + bias -> psT[b][r][8] ----
__global__ __launch_bounds__(256) void k_squash3(const float* __restrict__ pout,
    const float* __restrict__ bias, float* __restrict__ psT, int b0) {
  int s = blockIdx.x;        // 0..35
  int b_l = blockIdx.y;      // 0..127
  int t = threadIdx.x;
  int c32 = t & 31;
  __shared__ float ws[4][32];
  __shared__ float buf2[256];
  size_t base = ((size_t)(b_l * 36 + s)) * 256 + t;
  float val = bias[t];
#pragma unroll
  for (int k = 0; k < 9; ++k) val += pout[base + (size_t)k * 1179648];
  float v2 = val * val;
  v2 += __shfl_xor(v2, 32);
  int wvv = t >> 6, lane = t & 63;
  if (lane < 32) ws[wvv][lane] = v2;
  __syncthreads();
  float ss = ws[0][c32] + ws[1][c32] + ws[2][c32] + ws[3][c32];
  float sc = sqrtf(ss) / (1.f + ss);
  buf2[t] = val * sc;
  __syncthreads();
  int cc = t >> 3, jj = t & 7;
  psT[(size_t)(b0 + b_l) * 9216 + (size_t)cc * 288 + s * 8 + jj] =
      buf2[jj * 32 + cc];
}

// ---- fused routing v7: block = (class c, 2 batches); o-quartered priors in
//      registers; psT STAGED IN LDS (each p-vector read from HBM once per
//      block instead of 4x -> -21% VMEM instruction count). ----
__global__ __launch_bounds__(768) void k_route7(const float* __restrict__ psT,
    const float* __restrict__ rw, float* __restrict__ vout) {
  int c = blockIdx.x >> 7;
  int bp = blockIdx.x & 127;
  int b0 = bp * 2;
  int tid = threadIdx.x;
  int wave = tid >> 6, lane = tid & 63;
  int rl = lane & 15;
  int oq = lane >> 4;
  int rs = wave * 16 + rl;          // 0..191; r = rs + k*192
  __shared__ float ps_lds[2 * 9216];   // [b][r][8], 73.7 KB
  __shared__ float lreds[12][2];
  __shared__ float ored[12][4][2][4];
  __shared__ float vsq[2][16];

  // stage psT for both batches: 4608 float4, 6 per thread, coalesced
  {
    const float4* src = (const float4*)&psT[(size_t)b0 * 9216];
    float4* dst = (float4*)ps_lds;
#pragma unroll
    for (int j = 0; j < 6; ++j) dst[tid + j * 768] = src[tid + j * 768];
  }
  __syncthreads();

  float pri[2][6][4];
  float lgr[2][6];
#pragma unroll
  for (int b = 0; b < 2; ++b)
#pragma unroll
    for (int k = 0; k < 6; ++k) {
      lgr[b][k] = 0.f;
#pragma unroll
      for (int j = 0; j < 4; ++j) pri[b][k][j] = 0.f;
    }

  for (int k = 0; k < 6; ++k) {
    int r = rs + k * 192;
    const float* wr_ = &rw[((size_t)c * 1152 + r) * 128 + oq * 4];
    const float4* pp = (const float4*)&ps_lds[r * 8];
    const float4* pq = (const float4*)&ps_lds[9216 + r * 8];
    float4 pa0 = pp[0], pa1 = pp[1], pb0 = pq[0], pb1 = pq[1];
    float psa[8] = {pa0.x, pa0.y, pa0.z, pa0.w, pa1.x, pa1.y, pa1.z, pa1.w};
    float psb[8] = {pb0.x, pb0.y, pb0.z, pb0.w, pb1.x, pb1.y, pb1.z, pb1.w};
#pragma unroll
    for (int i = 0; i < 8; ++i) {
      float4 w4 = *(const float4*)&wr_[i * 16];
      float wa[4] = {w4.x, w4.y, w4.z, w4.w};
#pragma unroll
      for (int j = 0; j < 4; ++j) {
        pri[0][k][j] = fmaf(psa[i], wa[j], pri[0][k][j]);
        pri[1][k][j] = fmaf(psb[i], wa[j], pri[1][k][j]);
      }
    }
  }

  for (int it = 0; it < 3; ++it) {
    float a[2][4];
    if (it == 0) {
      const float invu = 1.f / 1152.f;
#pragma unroll
      for (int b = 0; b < 2; ++b)
#pragma unroll
        for (int j = 0; j < 4; ++j) {
          float s = 0.f;
#pragma unroll
          for (int k = 0; k < 6; ++k) s += pri[b][k][j];
          a[b][j] = s * invu;
        }
    } else {
      float sm[2] = {0.f, 0.f};
#pragma unroll
      for (int b = 0; b < 2; ++b)
#pragma unroll
        for (int k = 0; k < 6; ++k) sm[b] += __expf(lgr[b][k]);
#pragma unroll
      for (int off = 1; off < 16; off <<= 1)
#pragma unroll
        for (int b = 0; b < 2; ++b) sm[b] += __shfl_xor(sm[b], off);
      if (lane == 0) { lreds[wave][0] = sm[0]; lreds[wave][1] = sm[1]; }
      __syncthreads();
      float inv[2];
#pragma unroll
      for (int b = 0; b < 2; ++b) {
        float s = 0.f;
        for (int w = 0; w < 12; ++w) s += lreds[w][b];
        inv[b] = 1.f / s;
      }
#pragma unroll
      for (int b = 0; b < 2; ++b)
#pragma unroll
        for (int j = 0; j < 4; ++j) a[b][j] = 0.f;
#pragma unroll
      for (int k = 0; k < 6; ++k)
#pragma unroll
        for (int b = 0; b < 2; ++b) {
          float p = __expf(lgr[b][k]) * inv[b];
#pragma unroll
          for (int j = 0; j < 4; ++j) a[b][j] = fmaf(p, pri[b][k][j], a[b][j]);
        }
    }
#pragma unroll
    for (int off = 1; off < 16; off <<= 1)
#pragma unroll
      for (int b = 0; b < 2; ++b)
#pragma unroll
        for (int j = 0; j < 4; ++j) a[b][j] += __shfl_xor(a[b][j], off);
    if (rl == 0) {
#pragma unroll
      for (int b = 0; b < 2; ++b)
#pragma unroll
        for (int j = 0; j < 4; ++j) ored[wave][oq][b][j] = a[b][j];
    }
    __syncthreads();
    if (tid < 32) {
      int b = tid >> 4, o = tid & 15;
      float s = 0.f;
      for (int w = 0; w < 12; ++w) s += ored[w][o >> 2][b][o & 3];
      float s2 = s * s;
#pragma unroll
      for (int off = 1; off < 16; off <<= 1) s2 += __shfl_xor(s2, off);
      float sc = sqrtf(s2) / (1.f + s2);
      vsq[b][o] = s * sc;
    }
    __syncthreads();
    if (it < 2) {
#pragma unroll
      for (int b = 0; b < 2; ++b) {
        float vh[4];
#pragma unroll
        for (int j = 0; j < 4; ++j) vh[j] = vsq[b][oq * 4 + j];
#pragma unroll
        for (int k = 0; k < 6; ++k) {
          float d = 0.f;
#pragma unroll
          for (int j = 0; j < 4; ++j) d = fmaf(pri[b][k][j], vh[j], d);
          d += __shfl_xor(d, 16);
          d += __shfl_xor(d, 32);
          lgr[b][k] += d;
        }
      }
      __syncthreads();
    }
  }
  if (tid < 32) {
    int b = tid >> 4, o = tid & 15;
    vout[((size_t)c * BB + (b0 + b)) * 16 + o] = vsq[b][o];
  }
}

// ---- head: classes softmax + argmax + sparse fc1 (fused) ----
__global__ __launch_bounds__(512) void k_head(const float* __restrict__ v,
    const float* __restrict__ w1, const float* __restrict__ b1,
    float* __restrict__ classes, float* __restrict__ h1) {
  int b = blockIdx.x;
  int t = threadIdx.x;
  __shared__ float snrm[10];
  __shared__ float sv[16];
  __shared__ int sam;
  if (t < 10) {
    float sq = 0.f;
#pragma unroll
    for (int o = 0; o < 16; ++o) {
      float xx = v[(size_t)(t * BB + b) * 16 + o];
      sq += xx * xx;
    }
    snrm[t] = sqrtf(sq);
  }
  __syncthreads();
  if (t == 0) {
    int amx = 0;
    float bm = snrm[0];
    for (int cc = 1; cc < 10; ++cc)
      if (snrm[cc] > bm) { bm = snrm[cc]; amx = cc; }
    sam = amx;
  }
  __syncthreads();
  if (t < 10) {
    float mx = snrm[0];
    for (int cc = 1; cc < 10; ++cc) mx = fmaxf(mx, snrm[cc]);
    float smv = 0.f;
    for (int cc = 0; cc < 10; ++cc) smv += __expf(snrm[cc] - mx);
    classes[b * 10 + t] = __expf(snrm[t] - mx) / smv;
  }
  if (t < 16) sv[t] = v[((size_t)sam * BB + b) * 16 + t];
  __syncthreads();
  float acc = b1[t];
  int base = sam * 16;
#pragma unroll
  for (int i = 0; i < 16; ++i)
    acc = fmaf(sv[i], w1[(size_t)(base + i) * 512 + t], acc);
  h1[(size_t)b * 512 + t] = fmaxf(acc, 0.f);
}

// ---- fc 32x32-tile GEMM ----
template <int ACT>
__global__ __launch_bounds__(256) void k_fc32(const float* __restrict__ A,
                                              const float* __restrict__ W,
                                              const float* __restrict__ bias,
                                              float* __restrict__ O, int M,
                                              int N, int K) {
  int n0 = blockIdx.x * 32, m0 = blockIdx.y * 32;
  __shared__ float sa[32][33];
  __shared__ float sb[32][34];
  int tid = threadIdx.x, ty = tid >> 4, tx = tid & 15;
  float acc[2][2] = {};
  for (int k0 = 0; k0 < K; k0 += 32) {
    __syncthreads();
    for (int i = tid; i < 1024; i += 256) {
      int m = i >> 5, k = i & 31;
      sa[m][k] = A[(size_t)(m0 + m) * K + k0 + k];
      int kk = i >> 5, n = i & 31;
      int nn = n0 + n;
      sb[kk][n] = (nn < N) ? W[(size_t)(k0 + kk) * N + nn] : 0.f;
    }
    __syncthreads();
#pragma unroll
    for (int k = 0; k < 32; ++k) {
      float a0 = sa[ty * 2 + 0][k];
      float a1 = sa[ty * 2 + 1][k];
      float b0 = sb[k][tx * 2 + 0];
      float b1v = sb[k][tx * 2 + 1];
      acc[0][0] = fmaf(a0, b0, acc[0][0]);
      acc[0][1] = fmaf(a0, b1v, acc[0][1]);
      acc[1][0] = fmaf(a1, b0, acc[1][0]);
      acc[1][1] = fmaf(a1, b1v, acc[1][1]);
    }
  }
#pragma unroll
  for (int i = 0; i < 2; ++i) {
    int m = m0 + ty * 2 + i;
#pragma unroll
    for (int j = 0; j < 2; ++j) {
      int n = n0 + tx * 2 + j;
      if (n < N) {
        float xv = acc[i][j] + bias[n];
        if (ACT == 0)
          xv = fmaxf(xv, 0.f);
        else
          xv = 1.f / (1.f + expf(-xv));
        O[(size_t)m * N + n] = xv;
      }
    }
  }
}

extern "C" void kernel_launch(void* const* d_in, const int* in_sizes, int n_in,
                              void* d_out, int out_size, void* d_ws,
                              size_t ws_size, hipStream_t stream) {
  (void)in_sizes; (void)n_in; (void)out_size; (void)ws_size;
  const float* x       = (const float*)d_in[0];
  const float* conv1_w = (const float*)d_in[1];
  const float* conv1_b = (const float*)d_in[2];
  const float* prim_w  = (const float*)d_in[3];
  const float* prim_b  = (const float*)d_in[4];
  const float* route_w = (const float*)d_in[5];
  const float* dec_w1  = (const float*)d_in[6];
  const float* dec_b1  = (const float*)d_in[7];
  const float* dec_w2  = (const float*)d_in[8];
  const float* dec_b2  = (const float*)d_in[9];
  const float* dec_w3  = (const float*)d_in[10];
  const float* dec_b3  = (const float*)d_in[11];
  float* out = (float*)d_out;

  char* wsb = (char*)d_ws;
  __hip_bfloat16* hT_hi = (__hip_bfloat16*)(wsb);                 // 26,214,400 B
  __hip_bfloat16* hT_lo = (__hip_bfloat16*)(wsb + 26214400);      // 26,214,400 B
  __hip_bfloat16* wt_hi = (__hip_bfloat16*)(wsb + 52428800);      // 10,616,832 B
  __hip_bfloat16* wt_lo = (__hip_bfloat16*)(wsb + 63045632);      // 10,616,832 B
  float* pout = (float*)(wsb + 73662464);                         // 42,467,328 B (9 partials)
  float* psT  = (float*)(wsb + 116129792);                        //  9,437,184 B
  float* v    = (float*)(wsb + 125566976);                        //    163,840 B
  float* h1   = (float*)(wsb + 125730816);                        //    524,288 B
  float* h2   = (float*)(wsb + 126255104);                        //  1,048,576 B

  k_cvtw<<<1024, 256, 0, stream>>>(prim_w, wt_hi, wt_lo);
  for (int hh = 0; hh < 2; ++hh) {
    int b0 = hh * 128;
    k_conv1b<<<512, 256, 0, stream>>>(x, conv1_w, conv1_b, hT_hi, hT_lo, b0);
    k_prim6<<<720, 512, 0, stream>>>(hT_hi, hT_lo, wt_hi, wt_lo, pout);
    k_squash3<<<dim3(36, 128), 256, 0, stream>>>(pout, prim_b, psT, b0);
  }
  k_route7<<<1280, 768, 0, stream>>>(psT, route_w, v);
  k_head<<<256, 512, 0, stream>>>(v, dec_w1, dec_b1, out, h1);
  k_fc32<0><<<dim3(32, 8), 256, 0, stream>>>(h1, dec_w2, dec_b2, h2, 256, 1024, 512);
  k_fc32<1><<<dim3(25, 8), 256, 0, stream>>>(h2, dec_w3, dec_b3, out + 2560, 256, 784, 1024);
}